// Round 11
// baseline (181.329 us; speedup 1.0000x reference)
//
#include <hip/hip_runtime.h>
#include <hip/hip_bf16.h>
#include <stdint.h>

typedef __attribute__((ext_vector_type(8))) short short8;
typedef __attribute__((ext_vector_type(8))) unsigned short ushort8;
typedef __attribute__((ext_vector_type(4))) unsigned short ushort4v;
typedef __attribute__((ext_vector_type(4))) float f32x4;
typedef __attribute__((ext_vector_type(16))) float f32x16;

#define B_ 8
#define N_ 4096
#define C_ 256
#define D_ 32
#define LOG2E 1.44269504088896f

__device__ inline unsigned short f2bf(float f) {
  union { float f; unsigned u; } v; v.f = f;
  unsigned r = v.u + 0x7fffu + ((v.u >> 16) & 1u);
  return (unsigned short)(r >> 16);
}
__device__ inline float bf2f(unsigned short u) {
  return __uint_as_float(((unsigned)u) << 16);
}
__device__ inline float exp2_fast(float x) {
  float r; asm("v_exp_f32 %0, %1" : "=v"(r) : "v"(x)); return r;
}
__device__ inline unsigned cvt_pk_bf16(float lo, float hi) {
  unsigned r; asm("v_cvt_pk_bf16_f32 %0, %1, %2" : "=v"(r) : "v"(lo), "v"(hi)); return r;
}
// a <- [a.l0-31 | b.l0-31], b <- [a.l32-63 | b.l32-63]
__device__ inline void permlane32_swap(unsigned& a, unsigned& b) {
  asm volatile("v_permlane32_swap_b32 %0, %1" : "+v"(a), "+v"(b));
}
__device__ inline void gll16(const unsigned short* src, void* lds) {
  __builtin_amdgcn_global_load_lds((const __attribute__((address_space(1))) void*)src,
                                   (__attribute__((address_space(3))) void*)lds, 16, 0, 0);
}

// ---------------- kernel 0a: weight casts ----------------
// wcomb[320][256]: rows 0-31 w_q^T*log2e | 32-63 w_k^T | rows 64-319 filled by prep2.
__global__ __launch_bounds__(256) void prep_kernel(const float* __restrict__ wq,
                                                   const float* __restrict__ wk,
                                                   const float* __restrict__ wo,
                                                   const float* __restrict__ wv,
                                                   unsigned short* __restrict__ wcomb,
                                                   unsigned short* __restrict__ wv_b,
                                                   unsigned short* __restrict__ woT_b) {
  int i = blockIdx.x * 256 + threadIdx.x;  // total 147456
  if (i < 16384) {
    int row = i >> 8, kk = i & 255;
    float v = (row < 32) ? wq[kk * 32 + row] * LOG2E : wk[kk * 32 + (row - 32)];
    wcomb[i] = f2bf(v);
  } else if (i < 81920) {
    int j = i - 16384;
    wv_b[j] = f2bf(wv[j]);
  } else {
    int j = i - 81920;  // woT_b[e2][e] = wo[e][e2]
    int e2 = j >> 8, e = j & 255;
    woT_b[j] = f2bf(wo[e * 256 + e2]);
  }
}

// ---------------- kernel 0b: Wvo^T = Wo^T . Wv^T  (256x256, K=256) ----------------
__global__ __launch_bounds__(256) void prep2_kernel(const unsigned short* __restrict__ woT_b,
                                                    const unsigned short* __restrict__ wv_b,
                                                    unsigned short* __restrict__ wcomb) {
  const int lane = threadIdx.x & 63, w = threadIdx.x >> 6;
  const int g = lane >> 4, li = lane & 15;
  const int m0 = blockIdx.x * 64 + w * 16;
  const unsigned short* arow = woT_b + (size_t)(m0 + li) * 256 + (g << 3);
  const unsigned short* brow = wv_b + (size_t)li * 256 + (g << 3);
  f32x4 acc[16] = {};
  for (int kk = 0; kk < 256; kk += 32) {
    short8 a = *reinterpret_cast<const short8*>(arow + kk);
#pragma unroll
    for (int ct = 0; ct < 16; ++ct) {
      short8 bb = *reinterpret_cast<const short8*>(brow + (size_t)ct * 16 * 256 + kk);
      acc[ct] = __builtin_amdgcn_mfma_f32_16x16x32_bf16(a, bb, acc[ct], 0, 0, 0);
    }
  }
#pragma unroll
  for (int ct = 0; ct < 16; ++ct)
#pragma unroll
    for (int r = 0; r < 4; ++r)
      wcomb[(size_t)(64 + m0 + (g << 2) + r) * 256 + ct * 16 + li] = f2bf(acc[ct][r]);
}

// ---------------- kernel 1: fused QKVW projection, W staged in LDS ----------------
__global__ __launch_bounds__(256, 2) void qkv_kernel(const float* __restrict__ x,
                                                     const unsigned short* __restrict__ wcomb,
                                                     unsigned short* __restrict__ q,
                                                     unsigned short* __restrict__ k,
                                                     unsigned short* __restrict__ vwT) {
  __shared__ __align__(16) char wls[61440];  // 3 x 20480
  const int tid = threadIdx.x;
  const int l = tid & 63, w = tid >> 6;
  const int bx = blockIdx.x;
  const int g = l >> 4, li = l & 15;
  const int mt = bx * 64 + w * 16;
  const float* xrow = x + (size_t)(mt + li) * 256 + (g << 3);

  // ---- issue all x loads first (oldest in vm queue) ----
  f32x4 xf[16];
#pragma unroll
  for (int s = 0; s < 8; ++s) {
    xf[2 * s]     = *reinterpret_cast<const f32x4*>(xrow + s * 32);
    xf[2 * s + 1] = *reinterpret_cast<const f32x4*>(xrow + s * 32 + 4);
  }
  __builtin_amdgcn_sched_barrier(0);  // keep x loads older than W stages

#define WSTAGE(BUF, S)                                                              \
  {                                                                                 \
    _Pragma("unroll") for (int t = 0; t < 5; ++t) {                                 \
      const int ct = w * 5 + t;                                                     \
      gll16(wcomb + (size_t)(ct * 16 + (l >> 2)) * 256 + (S) * 32 +                 \
                (((l & 3) ^ ((l >> 2) & 3)) << 3),                                  \
            wls + (BUF) * 20480 + ct * 1024);                                       \
    }                                                                               \
  }

  WSTAGE(0, 0)
  WSTAGE(1, 1)

  short8 xb[8];
#pragma unroll
  for (int s = 0; s < 8; ++s) {
    union { unsigned u[4]; short8 v; } A;
    A.u[0] = cvt_pk_bf16(xf[2 * s][0], xf[2 * s][1]);
    A.u[1] = cvt_pk_bf16(xf[2 * s][2], xf[2 * s][3]);
    A.u[2] = cvt_pk_bf16(xf[2 * s + 1][0], xf[2 * s + 1][1]);
    A.u[3] = cvt_pk_bf16(xf[2 * s + 1][2], xf[2 * s + 1][3]);
    xb[s] = A.v;
  }

  f32x4 acc[20] = {};
  const int roff = li * 64 + ((g ^ (li & 3)) << 4);

#define QSTEP(S, BUF, WN, DOSTAGE)                                                  \
  {                                                                                 \
    asm volatile("s_waitcnt vmcnt(" WN ")" ::: "memory");                           \
    __builtin_amdgcn_sched_barrier(0);                                              \
    __builtin_amdgcn_s_barrier();                                                   \
    if (DOSTAGE) WSTAGE(((S) + 2) % 3, (S) + 2)                                     \
    const char* Wb = wls + (BUF) * 20480;                                           \
    _Pragma("unroll") for (int ct = 0; ct < 20; ++ct) {                             \
      short8 bb = *reinterpret_cast<const short8*>(Wb + ct * 1024 + roff);          \
      acc[ct] = __builtin_amdgcn_mfma_f32_16x16x32_bf16(xb[(S)], bb, acc[ct], 0, 0, 0); \
    }                                                                               \
  }

  QSTEP(0, 0, "5", true)
  QSTEP(1, 1, "5", true)
  QSTEP(2, 2, "5", true)
  QSTEP(3, 0, "5", true)
  QSTEP(4, 1, "5", true)
  QSTEP(5, 2, "5", true)
  QSTEP(6, 0, "5", false)
  QSTEP(7, 1, "0", false)

  const int bb_ = bx >> 6;
  const int nloc = (bx & 63) * 64 + w * 16 + (g << 2);
#pragma unroll
  for (int ct = 0; ct < 4; ++ct) {
    int col = ct * 16 + li;
    unsigned short* dst = (ct < 2) ? q : k;
    int cc = (ct < 2) ? col : col - 32;
#pragma unroll
    for (int r = 0; r < 4; ++r)
      dst[((size_t)bb_ * N_ + nloc + r) * D_ + cc] = f2bf(acc[ct][r]);
  }
#pragma unroll
  for (int ct = 4; ct < 20; ++ct) {
    int vcol = (ct - 4) * 16 + li;
    union { unsigned u[2]; ushort4v v; } P;
    P.u[0] = cvt_pk_bf16(acc[ct][0], acc[ct][1]);
    P.u[1] = cvt_pk_bf16(acc[ct][2], acc[ct][3]);
    *reinterpret_cast<ushort4v*>(&vwT[((size_t)bb_ * C_ + vcol) * N_ + nloc]) = P.v;
  }
#undef QSTEP
#undef WSTAGE
}

// ---------------- kernel 2: flash attention (64q x 64c waves, 3 blocks/CU) ----------
// grid 1024 x 256. blk: b = blk&7 (XCD pin); t = blk>>3: cs = t&1 (128-c half),
// kvh = (t>>1)&1, qt = t>>2 (0..31). Block tile 128q x 128c over 2048 kv
// (64 chunks of 32). 4 waves: qg = w>>1 (64q), cw = w&1 (64c). Wave 64q x 64c:
// acc = 4 x f32x16 = 64 AGPR; total regs ~160 -> 3 waves/SIMD (__launch_bounds__
// (256,3)), LDS 28672 -> 3 blocks/CU = 12 waves/CU. V triple-buffered 3x8KB staged
// 2-ahead, K double-buffered 2x2KB staged 1-ahead; uniform steady-state
// s_waitcnt vmcnt(2) (drains exactly chunk i for every wave), drained to 0 only at
// the last chunk; one s_barrier per chunk. P in registers (swapped S^T=K.Q^T,
// fixed m=0, q pre-scaled log2e); output projection folded into vwT. Writes
// unnormalized bf16 O partial + f32 lsum partial per kvh; merge_kernel sums.
__global__ __launch_bounds__(256, 3) void flash_kernel(const unsigned short* __restrict__ q,
                                                       const unsigned short* __restrict__ k,
                                                       const unsigned short* __restrict__ vwT,
                                                       unsigned short* __restrict__ opart,
                                                       float* __restrict__ lsumpart) {
  __shared__ __align__(16) char smem[28672];  // V 3x8192 @0 | K 2x2048 @24576
  const int tid = threadIdx.x;
  const int l = tid & 63, w_ = tid >> 6;
  const int qg = w_ >> 1, cw = w_ & 1;
  const int blk = blockIdx.x;
  const int b = blk & 7;
  const int t_ = blk >> 3;
  const int cs = t_ & 1, kvh = (t_ >> 1) & 1, qt = t_ >> 2;  // qt 0..31
  const int h = l >> 5, l31 = l & 31;

  const unsigned short* kb_ = k + (size_t)b * N_ * D_;
  const unsigned short* vb_ = vwT + (size_t)b * C_ * N_;

  // Q B-frags qb[qt2][ks]: col q = l31, k-dim = ks*16 + 8h + j
  const int qposb = qt * 128 + qg * 64;  // + qt2*32 + l31
  short8 qb[2][2];
#pragma unroll
  for (int qt2 = 0; qt2 < 2; ++qt2) {
    const size_t qoff = ((size_t)b * N_ + qposb + qt2 * 32 + l31) * D_ + h * 8;
    qb[qt2][0] = *reinterpret_cast<const short8*>(q + qoff);
    qb[qt2][1] = *reinterpret_cast<const short8*>(q + qoff + 16);
  }
  asm volatile("s_waitcnt vmcnt(0)" ::: "memory");  // clean vm counter before staging

  const int stg_row = l >> 2;
  const int stg_bk = ((l & 3) ^ ((l >> 3) & 3)) << 3;  // elems
  const int kvbase = kvh * 2048;
  const int cbase = cs * 128;

  // wave stages V local rows w_*32..+31 (2 gll16); waves 0,1 stage 16 K rows (1 gll16).
#define STAGE_V(BUF, KV0)                                                             \
  {                                                                                   \
    char* vd = smem + (BUF) * 8192 + w_ * 2048;                                       \
    gll16(vb_ + (size_t)(cbase + w_ * 32 + stg_row) * N_ + (KV0) + stg_bk, vd);       \
    gll16(vb_ + (size_t)(cbase + w_ * 32 + 16 + stg_row) * N_ + (KV0) + stg_bk,       \
          vd + 1024);                                                                 \
  }
#define STAGE_K(BUF, KV0)                                                             \
  {                                                                                   \
    if (w_ < 2)                                                                       \
      gll16(kb_ + (size_t)((KV0) + w_ * 16 + stg_row) * D_ + stg_bk,                  \
            smem + 24576 + (BUF) * 2048 + w_ * 1024);                                 \
  }

  f32x16 o[2][2] = {};  // [ct][qt2]: O^T (32c x 32q), c = cbase + cw*64 + ct*32
  float lsum[2] = {0.f, 0.f};
  const f32x16 z16 = {};

  // prologue: V(0), K(0), V(1) -> first-iter vmcnt(2) drains V(0)+K(0)
  STAGE_V(0, kvbase)
  STAGE_K(0, kvbase)
  STAGE_V(1, kvbase + 32)

  int cur = 0, nxt = 2;
  for (int i = 0; i < 64; ++i) {
    if (i < 63) { asm volatile("s_waitcnt vmcnt(2)" ::: "memory"); }
    else        { asm volatile("s_waitcnt vmcnt(0)" ::: "memory"); }
    __builtin_amdgcn_sched_barrier(0);
    __builtin_amdgcn_s_barrier();  // chunk i landed; all waves done with prev reads
    if (i < 63) STAGE_K((i + 1) & 1, kvbase + (i + 1) * 32)
    if (i < 62) STAGE_V(nxt, kvbase + (i + 2) * 32)
    const char* Vb = smem + cur * 8192;
    const char* Kb = smem + 24576 + (i & 1) * 2048;
    // ---- S^T[32kv][32q] = K . Q^T per qt2; exp; pack to PV B-frags ----
    const int kkey = (l31 >> 1) & 3;
    short8 ka0 = *reinterpret_cast<const short8*>(Kb + l31 * 64 + (((0 + h) ^ kkey) << 4));
    short8 ka1 = *reinterpret_cast<const short8*>(Kb + l31 * 64 + (((2 + h) ^ kkey) << 4));
    short8 pf[2][2];
#pragma unroll
    for (int qt2 = 0; qt2 < 2; ++qt2) {
      f32x16 s = __builtin_amdgcn_mfma_f32_32x32x16_bf16(ka0, qb[qt2][0], z16, 0, 0, 0);
      s = __builtin_amdgcn_mfma_f32_32x32x16_bf16(ka1, qb[qt2][1], s, 0, 0, 0);
      float p[16];
#pragma unroll
      for (int r = 0; r < 16; ++r) p[r] = exp2_fast(s[r]);
      lsum[qt2] += (((p[0] + p[1]) + (p[2] + p[3])) + ((p[4] + p[5]) + (p[6] + p[7]))) +
                   (((p[8] + p[9]) + (p[10] + p[11])) + ((p[12] + p[13]) + (p[14] + p[15])));
      unsigned x0 = cvt_pk_bf16(p[0], p[1]),   y0 = cvt_pk_bf16(p[4], p[5]);
      unsigned x1 = cvt_pk_bf16(p[2], p[3]),   y1 = cvt_pk_bf16(p[6], p[7]);
      unsigned x2 = cvt_pk_bf16(p[8], p[9]),   y2 = cvt_pk_bf16(p[12], p[13]);
      unsigned x3 = cvt_pk_bf16(p[10], p[11]), y3 = cvt_pk_bf16(p[14], p[15]);
      permlane32_swap(x0, y0); permlane32_swap(x1, y1);
      permlane32_swap(x2, y2); permlane32_swap(x3, y3);
      union U { unsigned u[4]; short8 v; };
      U u0; u0.u[0] = x0; u0.u[1] = x1; u0.u[2] = y0; u0.u[3] = y1;  // kv 0-15
      U u1; u1.u[0] = x2; u1.u[1] = x3; u1.u[2] = y2; u1.u[3] = y3;  // kv 16-31
      pf[qt2][0] = u0.v; pf[qt2][1] = u1.v;
    }
    // ---- PV: O^T[c][q] += V^T . P^T (each va read feeds both qt2) ----
    __builtin_amdgcn_s_setprio(1);
#pragma unroll
    for (int ct = 0; ct < 2; ++ct) {
      const int rl = cw * 64 + ct * 32 + l31;
      const int vkey = (rl >> 1) & 3;
      short8 va0 = *reinterpret_cast<const short8*>(Vb + rl * 64 + (((0 + h) ^ vkey) << 4));
      short8 va1 = *reinterpret_cast<const short8*>(Vb + rl * 64 + (((2 + h) ^ vkey) << 4));
      o[ct][0] = __builtin_amdgcn_mfma_f32_32x32x16_bf16(va0, pf[0][0], o[ct][0], 0, 0, 0);
      o[ct][0] = __builtin_amdgcn_mfma_f32_32x32x16_bf16(va1, pf[0][1], o[ct][0], 0, 0, 0);
      o[ct][1] = __builtin_amdgcn_mfma_f32_32x32x16_bf16(va0, pf[1][0], o[ct][1], 0, 0, 0);
      o[ct][1] = __builtin_amdgcn_mfma_f32_32x32x16_bf16(va1, pf[1][1], o[ct][1], 0, 0, 0);
    }
    __builtin_amdgcn_s_setprio(0);
    cur = (cur == 2) ? 0 : cur + 1;
    nxt = (nxt == 2) ? 0 : nxt + 1;
  }

  // ---- epilogue: unnormalized bf16 O partial + f32 lsum partial ----
  lsum[0] += __shfl_xor(lsum[0], 32);
  lsum[1] += __shfl_xor(lsum[1], 32);
  unsigned short* op = opart + ((size_t)kvh * B_ + b) * (size_t)N_ * C_;
#pragma unroll
  for (int qt2 = 0; qt2 < 2; ++qt2) {
    const size_t rowoff = (size_t)(qposb + qt2 * 32 + l31) * C_ + cbase + cw * 64;
#pragma unroll
    for (int ct = 0; ct < 2; ++ct)
#pragma unroll
      for (int j = 0; j < 8; ++j) {
        const int c = ct * 32 + 2 * (j & 1) + 8 * (j >> 1) + 4 * h;
        unsigned wv = cvt_pk_bf16(o[ct][qt2][2 * j], o[ct][qt2][2 * j + 1]);
        *reinterpret_cast<unsigned*>(&op[rowoff + c]) = wv;
      }
  }
  if (h == 0 && cw == 0 && cs == 0) {
    float* lp = lsumpart + ((size_t)kvh * B_ + b) * N_ + qposb;
    lp[l31] = lsum[0];
    lp[32 + l31] = lsum[1];
  }
#undef STAGE_V
#undef STAGE_K
}

// ---------------- kernel 3: merge kv-split partials + residual ----------------
// out = x + (O0 + O1) / (l0 + l1).  8192 blocks x 256 thr x one f32x4 group.
__global__ __launch_bounds__(256) void merge_kernel(const unsigned short* __restrict__ opart,
                                                    const float* __restrict__ lsumpart,
                                                    const float* __restrict__ x,
                                                    float* __restrict__ out) {
  const int i4 = blockIdx.x * 256 + threadIdx.x;  // f32x4 group, total 2097152
  const int m = i4 >> 6;                          // row (64 groups per 256-c row)
  const float inv = 1.0f / (lsumpart[m] + lsumpart[B_ * N_ + m]);
  ushort4v a0 = *reinterpret_cast<const ushort4v*>(opart + (size_t)i4 * 4);
  ushort4v a1 = *reinterpret_cast<const ushort4v*>(opart + (size_t)B_ * N_ * C_ + (size_t)i4 * 4);
  f32x4 xr = *reinterpret_cast<const f32x4*>(x + (size_t)i4 * 4);
  f32x4 t;
  t[0] = xr[0] + (bf2f(a0[0]) + bf2f(a1[0])) * inv;
  t[1] = xr[1] + (bf2f(a0[1]) + bf2f(a1[1])) * inv;
  t[2] = xr[2] + (bf2f(a0[2]) + bf2f(a1[2])) * inv;
  t[3] = xr[3] + (bf2f(a0[3]) + bf2f(a1[3])) * inv;
  *reinterpret_cast<f32x4*>(out + (size_t)i4 * 4) = t;
}

extern "C" void kernel_launch(void* const* d_in, const int* in_sizes, int n_in,
                              void* d_out, int out_size, void* d_ws, size_t ws_size,
                              hipStream_t stream) {
  const float* x  = (const float*)d_in[0];
  const float* wq = (const float*)d_in[1];
  const float* wk = (const float*)d_in[2];
  const float* wv = (const float*)d_in[3];
  const float* wo = (const float*)d_in[4];
  float* out = (float*)d_out;
  char* ws = (char*)d_ws;
  unsigned short* wcomb = (unsigned short*)(ws + 0);         // 163840 B
  unsigned short* wv_b  = (unsigned short*)(ws + 163840);    // 131072 B
  unsigned short* woT_b = (unsigned short*)(ws + 294912);    // 131072 B
  unsigned short* q     = (unsigned short*)(ws + 425984);    // 2 MB
  unsigned short* k     = (unsigned short*)(ws + 2523136);   // 2 MB
  unsigned short* vwT   = (unsigned short*)(ws + 4620288);   // 16 MB
  unsigned short* opart = (unsigned short*)(ws + 21397504);  // 32 MB (2 parts)
  float*          lsump = (float*)(ws + 54951936);           // 256 KB (total ~55.2 MB)

  prep_kernel<<<576, 256, 0, stream>>>(wq, wk, wo, wv, wcomb, wv_b, woT_b);
  prep2_kernel<<<4, 256, 0, stream>>>(woT_b, wv_b, wcomb);
  qkv_kernel<<<512, 256, 0, stream>>>(x, wcomb, q, k, vwT);
  flash_kernel<<<1024, 256, 0, stream>>>(q, k, vwT, opart, lsump);
  merge_kernel<<<8192, 256, 0, stream>>>(opart, lsump, x, out);
}

// Round 12
// 154.743 us; speedup vs baseline: 1.1718x; 1.1718x over previous
//
#include <hip/hip_runtime.h>
#include <hip/hip_bf16.h>
#include <stdint.h>

typedef __attribute__((ext_vector_type(8))) short short8;
typedef __attribute__((ext_vector_type(8))) unsigned short ushort8;
typedef __attribute__((ext_vector_type(4))) unsigned short ushort4v;
typedef __attribute__((ext_vector_type(4))) float f32x4;
typedef __attribute__((ext_vector_type(16))) float f32x16;

#define B_ 8
#define N_ 4096
#define C_ 256
#define D_ 32
#define LOG2E 1.44269504088896f

__device__ inline unsigned short f2bf(float f) {
  union { float f; unsigned u; } v; v.f = f;
  unsigned r = v.u + 0x7fffu + ((v.u >> 16) & 1u);
  return (unsigned short)(r >> 16);
}
__device__ inline float bf2f(unsigned short u) {
  return __uint_as_float(((unsigned)u) << 16);
}
__device__ inline float exp2_fast(float x) {
  float r; asm("v_exp_f32 %0, %1" : "=v"(r) : "v"(x)); return r;
}
__device__ inline unsigned cvt_pk_bf16(float lo, float hi) {
  unsigned r; asm("v_cvt_pk_bf16_f32 %0, %1, %2" : "=v"(r) : "v"(lo), "v"(hi)); return r;
}
// a <- [a.l0-31 | b.l0-31], b <- [a.l32-63 | b.l32-63]
__device__ inline void permlane32_swap(unsigned& a, unsigned& b) {
  asm volatile("v_permlane32_swap_b32 %0, %1" : "+v"(a), "+v"(b));
}
__device__ inline void gll16(const unsigned short* src, void* lds) {
  __builtin_amdgcn_global_load_lds((const __attribute__((address_space(1))) void*)src,
                                   (__attribute__((address_space(3))) void*)lds, 16, 0, 0);
}

// ---------------- kernel 0a: weight casts ----------------
// wcomb[320][256]: rows 0-31 w_q^T*log2e | 32-63 w_k^T | rows 64-319 filled by prep2.
__global__ __launch_bounds__(256) void prep_kernel(const float* __restrict__ wq,
                                                   const float* __restrict__ wk,
                                                   const float* __restrict__ wo,
                                                   const float* __restrict__ wv,
                                                   unsigned short* __restrict__ wcomb,
                                                   unsigned short* __restrict__ wv_b,
                                                   unsigned short* __restrict__ woT_b) {
  int i = blockIdx.x * 256 + threadIdx.x;  // total 147456
  if (i < 16384) {
    int row = i >> 8, kk = i & 255;
    float v = (row < 32) ? wq[kk * 32 + row] * LOG2E : wk[kk * 32 + (row - 32)];
    wcomb[i] = f2bf(v);
  } else if (i < 81920) {
    int j = i - 16384;
    wv_b[j] = f2bf(wv[j]);
  } else {
    int j = i - 81920;  // woT_b[e2][e] = wo[e][e2]
    int e2 = j >> 8, e = j & 255;
    woT_b[j] = f2bf(wo[e * 256 + e2]);
  }
}

// ---------------- kernel 0b: Wvo^T = Wo^T . Wv^T  (256x256, K=256) ----------------
__global__ __launch_bounds__(256) void prep2_kernel(const unsigned short* __restrict__ woT_b,
                                                    const unsigned short* __restrict__ wv_b,
                                                    unsigned short* __restrict__ wcomb) {
  const int lane = threadIdx.x & 63, w = threadIdx.x >> 6;
  const int g = lane >> 4, li = lane & 15;
  const int m0 = blockIdx.x * 64 + w * 16;
  const unsigned short* arow = woT_b + (size_t)(m0 + li) * 256 + (g << 3);
  const unsigned short* brow = wv_b + (size_t)li * 256 + (g << 3);
  f32x4 acc[16] = {};
  for (int kk = 0; kk < 256; kk += 32) {
    short8 a = *reinterpret_cast<const short8*>(arow + kk);
#pragma unroll
    for (int ct = 0; ct < 16; ++ct) {
      short8 bb = *reinterpret_cast<const short8*>(brow + (size_t)ct * 16 * 256 + kk);
      acc[ct] = __builtin_amdgcn_mfma_f32_16x16x32_bf16(a, bb, acc[ct], 0, 0, 0);
    }
  }
#pragma unroll
  for (int ct = 0; ct < 16; ++ct)
#pragma unroll
    for (int r = 0; r < 4; ++r)
      wcomb[(size_t)(64 + m0 + (g << 2) + r) * 256 + ct * 16 + li] = f2bf(acc[ct][r]);
}

// ---------------- kernel 1: fused QKVW projection, W staged in LDS ----------------
__global__ __launch_bounds__(256, 2) void qkv_kernel(const float* __restrict__ x,
                                                     const unsigned short* __restrict__ wcomb,
                                                     unsigned short* __restrict__ q,
                                                     unsigned short* __restrict__ k,
                                                     unsigned short* __restrict__ vwT) {
  __shared__ __align__(16) char wls[61440];  // 3 x 20480
  const int tid = threadIdx.x;
  const int l = tid & 63, w = tid >> 6;
  const int bx = blockIdx.x;
  const int g = l >> 4, li = l & 15;
  const int mt = bx * 64 + w * 16;
  const float* xrow = x + (size_t)(mt + li) * 256 + (g << 3);

  // ---- issue all x loads first (oldest in vm queue) ----
  f32x4 xf[16];
#pragma unroll
  for (int s = 0; s < 8; ++s) {
    xf[2 * s]     = *reinterpret_cast<const f32x4*>(xrow + s * 32);
    xf[2 * s + 1] = *reinterpret_cast<const f32x4*>(xrow + s * 32 + 4);
  }
  __builtin_amdgcn_sched_barrier(0);  // keep x loads older than W stages

#define WSTAGE(BUF, S)                                                              \
  {                                                                                 \
    _Pragma("unroll") for (int t = 0; t < 5; ++t) {                                 \
      const int ct = w * 5 + t;                                                     \
      gll16(wcomb + (size_t)(ct * 16 + (l >> 2)) * 256 + (S) * 32 +                 \
                (((l & 3) ^ ((l >> 2) & 3)) << 3),                                  \
            wls + (BUF) * 20480 + ct * 1024);                                       \
    }                                                                               \
  }

  WSTAGE(0, 0)
  WSTAGE(1, 1)

  short8 xb[8];
#pragma unroll
  for (int s = 0; s < 8; ++s) {
    union { unsigned u[4]; short8 v; } A;
    A.u[0] = cvt_pk_bf16(xf[2 * s][0], xf[2 * s][1]);
    A.u[1] = cvt_pk_bf16(xf[2 * s][2], xf[2 * s][3]);
    A.u[2] = cvt_pk_bf16(xf[2 * s + 1][0], xf[2 * s + 1][1]);
    A.u[3] = cvt_pk_bf16(xf[2 * s + 1][2], xf[2 * s + 1][3]);
    xb[s] = A.v;
  }

  f32x4 acc[20] = {};
  const int roff = li * 64 + ((g ^ (li & 3)) << 4);

#define QSTEP(S, BUF, WN, DOSTAGE)                                                  \
  {                                                                                 \
    asm volatile("s_waitcnt vmcnt(" WN ")" ::: "memory");                           \
    __builtin_amdgcn_sched_barrier(0);                                              \
    __builtin_amdgcn_s_barrier();                                                   \
    if (DOSTAGE) WSTAGE(((S) + 2) % 3, (S) + 2)                                     \
    const char* Wb = wls + (BUF) * 20480;                                           \
    _Pragma("unroll") for (int ct = 0; ct < 20; ++ct) {                             \
      short8 bb = *reinterpret_cast<const short8*>(Wb + ct * 1024 + roff);          \
      acc[ct] = __builtin_amdgcn_mfma_f32_16x16x32_bf16(xb[(S)], bb, acc[ct], 0, 0, 0); \
    }                                                                               \
  }

  QSTEP(0, 0, "5", true)
  QSTEP(1, 1, "5", true)
  QSTEP(2, 2, "5", true)
  QSTEP(3, 0, "5", true)
  QSTEP(4, 1, "5", true)
  QSTEP(5, 2, "5", true)
  QSTEP(6, 0, "5", false)
  QSTEP(7, 1, "0", false)

  const int bb_ = bx >> 6;
  const int nloc = (bx & 63) * 64 + w * 16 + (g << 2);
#pragma unroll
  for (int ct = 0; ct < 4; ++ct) {
    int col = ct * 16 + li;
    unsigned short* dst = (ct < 2) ? q : k;
    int cc = (ct < 2) ? col : col - 32;
#pragma unroll
    for (int r = 0; r < 4; ++r)
      dst[((size_t)bb_ * N_ + nloc + r) * D_ + cc] = f2bf(acc[ct][r]);
  }
#pragma unroll
  for (int ct = 4; ct < 20; ++ct) {
    int vcol = (ct - 4) * 16 + li;
    union { unsigned u[2]; ushort4v v; } P;
    P.u[0] = cvt_pk_bf16(acc[ct][0], acc[ct][1]);
    P.u[1] = cvt_pk_bf16(acc[ct][2], acc[ct][3]);
    *reinterpret_cast<ushort4v*>(&vwT[((size_t)bb_ * C_ + vcol) * N_ + nloc]) = P.v;
  }
#undef QSTEP
#undef WSTAGE
}

// ---------------- kernel 2: flash attention (r10 geometry, pipelined iter body) ----
// grid 512 x 256. blk: b = blk&7 (XCD pin), kvh = (blk>>3)&1, qt = blk>>4 (0..31).
// Block tile 128q x 256c over 2048 kv (64 chunks of 32). 4 waves: qg = w>>1, ch = w&1;
// wave = 64q x 128c (two 32q subtiles qt2 -> each V-frag read feeds 2 PV MFMAs).
// V triple-buffered 3x16KB staged 2-ahead; K double-buffered 2x2KB staged 1-ahead;
// uniform steady-state vmcnt(4), one s_barrier per chunk (r10-proven).
// NEW vs r10: (1) both qt2 S-MFMA pairs issued back-to-back before any VALU;
// (2) exp2 in-place into s (kills p[16] array); (3) lsum only on ch==0 waves
// (ch==1's was discarded); (4) PV orders qt2=0 MFMAs first (can start pre-pack1).
__global__ __launch_bounds__(256, 2) void flash_kernel(const unsigned short* __restrict__ q,
                                                       const unsigned short* __restrict__ k,
                                                       const unsigned short* __restrict__ vwT,
                                                       unsigned short* __restrict__ opart,
                                                       float* __restrict__ lsumpart) {
  __shared__ __align__(16) char smem[53248];  // V 3x16384 @0 | K 2x2048 @49152
  const int tid = threadIdx.x;
  const int l = tid & 63, w_ = tid >> 6;
  const int qg = w_ >> 1, ch = w_ & 1;
  const int blk = blockIdx.x;
  const int b = blk & 7;
  const int kvh = (blk >> 3) & 1;
  const int qt = blk >> 4;  // 0..31
  const int h = l >> 5, l31 = l & 31;

  const unsigned short* kb_ = k + (size_t)b * N_ * D_;
  const unsigned short* vb_ = vwT + (size_t)b * C_ * N_;

  // Q B-frags qb[qt2][ks]: col q = l31, k-dim = ks*16 + 8h + j
  const int qposb = qt * 128 + qg * 64;  // + qt2*32 + l31
  short8 qb[2][2];
#pragma unroll
  for (int qt2 = 0; qt2 < 2; ++qt2) {
    const size_t qoff = ((size_t)b * N_ + qposb + qt2 * 32 + l31) * D_ + h * 8;
    qb[qt2][0] = *reinterpret_cast<const short8*>(q + qoff);
    qb[qt2][1] = *reinterpret_cast<const short8*>(q + qoff + 16);
  }
  asm volatile("s_waitcnt vmcnt(0)" ::: "memory");  // clean vm counter before staging

  const int stg_row = l >> 2;
  const int stg_bk = ((l & 3) ^ ((l >> 3) & 3)) << 3;  // elems
  const int kvbase = kvh * 2048;

  // wave stages V rows w_*64..+63 (4 gll16); waves 0,1 stage 16 K rows each (1 gll16).
#define STAGE_V(BUF, KV0)                                                         \
  {                                                                               \
    char* vd = smem + (BUF) * 16384 + w_ * 4096;                                  \
    _Pragma("unroll") for (int t = 0; t < 4; ++t)                                 \
        gll16(vb_ + (size_t)(w_ * 64 + t * 16 + stg_row) * N_ + (KV0) + stg_bk,   \
              vd + t * 1024);                                                     \
  }
#define STAGE_K(BUF, KV0)                                                         \
  {                                                                               \
    if (w_ < 2)                                                                   \
      gll16(kb_ + (size_t)((KV0) + w_ * 16 + stg_row) * D_ + stg_bk,              \
            smem + 49152 + (BUF) * 2048 + w_ * 1024);                             \
  }

  f32x16 o[4][2] = {};  // [ct][qt2]: O^T (32c x 32q), c = ch*128 + ct*32
  float lsum[2] = {0.f, 0.f};
  const f32x16 z16 = {};

  // prologue: V(0), K(0), V(1)  -> first-iter vmcnt(4) drains V(0)+K(0)
  STAGE_V(0, kvbase)
  STAGE_K(0, kvbase)
  STAGE_V(1, kvbase + 32)

  int cur = 0, nxt = 2;
  for (int i = 0; i < 64; ++i) {
    if (i < 63) { asm volatile("s_waitcnt vmcnt(4)" ::: "memory"); }
    else        { asm volatile("s_waitcnt vmcnt(0)" ::: "memory"); }
    __builtin_amdgcn_sched_barrier(0);
    __builtin_amdgcn_s_barrier();  // chunk i landed; all waves done with prev reads
    if (i < 63) STAGE_K((i + 1) & 1, kvbase + (i + 1) * 32)
    if (i < 62) STAGE_V(nxt, kvbase + (i + 2) * 32)
    const char* Vb = smem + cur * 16384;
    const char* Kb = smem + 49152 + (i & 1) * 2048;
    // ---- both S^T = K.Q^T pairs back-to-back (MFMA pipe burst) ----
    const int kkey = (l31 >> 1) & 3;
    short8 ka0 = *reinterpret_cast<const short8*>(Kb + l31 * 64 + (((0 + h) ^ kkey) << 4));
    short8 ka1 = *reinterpret_cast<const short8*>(Kb + l31 * 64 + (((2 + h) ^ kkey) << 4));
    f32x16 s0 = __builtin_amdgcn_mfma_f32_32x32x16_bf16(ka0, qb[0][0], z16, 0, 0, 0);
    s0 = __builtin_amdgcn_mfma_f32_32x32x16_bf16(ka1, qb[0][1], s0, 0, 0, 0);
    f32x16 s1 = __builtin_amdgcn_mfma_f32_32x32x16_bf16(ka0, qb[1][0], z16, 0, 0, 0);
    s1 = __builtin_amdgcn_mfma_f32_32x32x16_bf16(ka1, qb[1][1], s1, 0, 0, 0);
    // ---- exp in place; lsum only where it's consumed (ch==0) ----
    short8 pf[2][2];
#pragma unroll
    for (int r = 0; r < 16; ++r) s0[r] = exp2_fast(s0[r]);
    if (ch == 0)
      lsum[0] += (((s0[0] + s0[1]) + (s0[2] + s0[3])) + ((s0[4] + s0[5]) + (s0[6] + s0[7]))) +
                 (((s0[8] + s0[9]) + (s0[10] + s0[11])) + ((s0[12] + s0[13]) + (s0[14] + s0[15])));
    {
      unsigned x0 = cvt_pk_bf16(s0[0], s0[1]),   y0 = cvt_pk_bf16(s0[4], s0[5]);
      unsigned x1 = cvt_pk_bf16(s0[2], s0[3]),   y1 = cvt_pk_bf16(s0[6], s0[7]);
      unsigned x2 = cvt_pk_bf16(s0[8], s0[9]),   y2 = cvt_pk_bf16(s0[12], s0[13]);
      unsigned x3 = cvt_pk_bf16(s0[10], s0[11]), y3 = cvt_pk_bf16(s0[14], s0[15]);
      permlane32_swap(x0, y0); permlane32_swap(x1, y1);
      permlane32_swap(x2, y2); permlane32_swap(x3, y3);
      union U { unsigned u[4]; short8 v; };
      U u0; u0.u[0] = x0; u0.u[1] = x1; u0.u[2] = y0; u0.u[3] = y1;  // kv 0-15
      U u1; u1.u[0] = x2; u1.u[1] = x3; u1.u[2] = y2; u1.u[3] = y3;  // kv 16-31
      pf[0][0] = u0.v; pf[0][1] = u1.v;
    }
#pragma unroll
    for (int r = 0; r < 16; ++r) s1[r] = exp2_fast(s1[r]);
    if (ch == 0)
      lsum[1] += (((s1[0] + s1[1]) + (s1[2] + s1[3])) + ((s1[4] + s1[5]) + (s1[6] + s1[7]))) +
                 (((s1[8] + s1[9]) + (s1[10] + s1[11])) + ((s1[12] + s1[13]) + (s1[14] + s1[15])));
    {
      unsigned x0 = cvt_pk_bf16(s1[0], s1[1]),   y0 = cvt_pk_bf16(s1[4], s1[5]);
      unsigned x1 = cvt_pk_bf16(s1[2], s1[3]),   y1 = cvt_pk_bf16(s1[6], s1[7]);
      unsigned x2 = cvt_pk_bf16(s1[8], s1[9]),   y2 = cvt_pk_bf16(s1[12], s1[13]);
      unsigned x3 = cvt_pk_bf16(s1[10], s1[11]), y3 = cvt_pk_bf16(s1[14], s1[15]);
      permlane32_swap(x0, y0); permlane32_swap(x1, y1);
      permlane32_swap(x2, y2); permlane32_swap(x3, y3);
      union U { unsigned u[4]; short8 v; };
      U u0; u0.u[0] = x0; u0.u[1] = x1; u0.u[2] = y0; u0.u[3] = y1;
      U u1; u1.u[0] = x2; u1.u[1] = x3; u1.u[2] = y2; u1.u[3] = y3;
      pf[1][0] = u0.v; pf[1][1] = u1.v;
    }
    // ---- PV: O^T[c][q] += V^T . P^T (qt2=0 MFMAs first; va feeds both qt2) ----
    __builtin_amdgcn_s_setprio(1);
#pragma unroll
    for (int ct = 0; ct < 4; ++ct) {
      const int rl = ch * 128 + ct * 32 + l31;
      const int vkey = (rl >> 1) & 3;
      short8 va0 = *reinterpret_cast<const short8*>(Vb + rl * 64 + (((0 + h) ^ vkey) << 4));
      short8 va1 = *reinterpret_cast<const short8*>(Vb + rl * 64 + (((2 + h) ^ vkey) << 4));
      o[ct][0] = __builtin_amdgcn_mfma_f32_32x32x16_bf16(va0, pf[0][0], o[ct][0], 0, 0, 0);
      o[ct][0] = __builtin_amdgcn_mfma_f32_32x32x16_bf16(va1, pf[0][1], o[ct][0], 0, 0, 0);
      o[ct][1] = __builtin_amdgcn_mfma_f32_32x32x16_bf16(va0, pf[1][0], o[ct][1], 0, 0, 0);
      o[ct][1] = __builtin_amdgcn_mfma_f32_32x32x16_bf16(va1, pf[1][1], o[ct][1], 0, 0, 0);
    }
    __builtin_amdgcn_s_setprio(0);
    cur = (cur == 2) ? 0 : cur + 1;
    nxt = (nxt == 2) ? 0 : nxt + 1;
  }

  // ---- epilogue: unnormalized bf16 O partial + f32 lsum partial ----
  lsum[0] += __shfl_xor(lsum[0], 32);
  lsum[1] += __shfl_xor(lsum[1], 32);
  unsigned short* op = opart + ((size_t)kvh * B_ + b) * (size_t)N_ * C_;
#pragma unroll
  for (int qt2 = 0; qt2 < 2; ++qt2) {
    const size_t rowoff = (size_t)(qposb + qt2 * 32 + l31) * C_ + ch * 128;
#pragma unroll
    for (int ct = 0; ct < 4; ++ct)
#pragma unroll
      for (int j = 0; j < 8; ++j) {
        const int c = ct * 32 + 2 * (j & 1) + 8 * (j >> 1) + 4 * h;
        unsigned wv = cvt_pk_bf16(o[ct][qt2][2 * j], o[ct][qt2][2 * j + 1]);
        *reinterpret_cast<unsigned*>(&op[rowoff + c]) = wv;
      }
  }
  if (h == 0 && ch == 0) {
    float* lp = lsumpart + ((size_t)kvh * B_ + b) * N_ + qposb;
    lp[l31] = lsum[0];
    lp[32 + l31] = lsum[1];
  }
#undef STAGE_V
#undef STAGE_K
}

// ---------------- kernel 3: merge kv-split partials + residual ----------------
// out = x + (O0 + O1) / (l0 + l1).  8192 blocks x 256 thr x one f32x4 group.
__global__ __launch_bounds__(256) void merge_kernel(const unsigned short* __restrict__ opart,
                                                    const float* __restrict__ lsumpart,
                                                    const float* __restrict__ x,
                                                    float* __restrict__ out) {
  const int i4 = blockIdx.x * 256 + threadIdx.x;  // f32x4 group, total 2097152
  const int m = i4 >> 6;                          // row (64 groups per 256-c row)
  const float inv = 1.0f / (lsumpart[m] + lsumpart[B_ * N_ + m]);
  ushort4v a0 = *reinterpret_cast<const ushort4v*>(opart + (size_t)i4 * 4);
  ushort4v a1 = *reinterpret_cast<const ushort4v*>(opart + (size_t)B_ * N_ * C_ + (size_t)i4 * 4);
  f32x4 xr = *reinterpret_cast<const f32x4*>(x + (size_t)i4 * 4);
  f32x4 t;
  t[0] = xr[0] + (bf2f(a0[0]) + bf2f(a1[0])) * inv;
  t[1] = xr[1] + (bf2f(a0[1]) + bf2f(a1[1])) * inv;
  t[2] = xr[2] + (bf2f(a0[2]) + bf2f(a1[2])) * inv;
  t[3] = xr[3] + (bf2f(a0[3]) + bf2f(a1[3])) * inv;
  *reinterpret_cast<f32x4*>(out + (size_t)i4 * 4) = t;
}

extern "C" void kernel_launch(void* const* d_in, const int* in_sizes, int n_in,
                              void* d_out, int out_size, void* d_ws, size_t ws_size,
                              hipStream_t stream) {
  const float* x  = (const float*)d_in[0];
  const float* wq = (const float*)d_in[1];
  const float* wk = (const float*)d_in[2];
  const float* wv = (const float*)d_in[3];
  const float* wo = (const float*)d_in[4];
  float* out = (float*)d_out;
  char* ws = (char*)d_ws;
  unsigned short* wcomb = (unsigned short*)(ws + 0);         // 163840 B
  unsigned short* wv_b  = (unsigned short*)(ws + 163840);    // 131072 B
  unsigned short* woT_b = (unsigned short*)(ws + 294912);    // 131072 B
  unsigned short* q     = (unsigned short*)(ws + 425984);    // 2 MB
  unsigned short* k     = (unsigned short*)(ws + 2523136);   // 2 MB
  unsigned short* vwT   = (unsigned short*)(ws + 4620288);   // 16 MB
  unsigned short* opart = (unsigned short*)(ws + 21397504);  // 32 MB (2 parts)
  float*          lsump = (float*)(ws + 54951936);           // 256 KB (total ~55.2 MB)

  prep_kernel<<<576, 256, 0, stream>>>(wq, wk, wo, wv, wcomb, wv_b, woT_b);
  prep2_kernel<<<4, 256, 0, stream>>>(woT_b, wv_b, wcomb);
  qkv_kernel<<<512, 256, 0, stream>>>(x, wcomb, q, k, vwT);
  flash_kernel<<<512, 256, 0, stream>>>(q, k, vwT, opart, lsump);
  merge_kernel<<<8192, 256, 0, stream>>>(opart, lsump, x, out);
}

// Round 13
// 153.553 us; speedup vs baseline: 1.1809x; 1.0078x over previous
//
#include <hip/hip_runtime.h>
#include <hip/hip_bf16.h>
#include <stdint.h>

typedef __attribute__((ext_vector_type(8))) short short8;
typedef __attribute__((ext_vector_type(8))) unsigned short ushort8;
typedef __attribute__((ext_vector_type(4))) unsigned short ushort4v;
typedef __attribute__((ext_vector_type(4))) float f32x4;
typedef __attribute__((ext_vector_type(16))) float f32x16;

#define B_ 8
#define N_ 4096
#define C_ 256
#define D_ 32
#define LOG2E 1.44269504088896f

__device__ inline unsigned short f2bf(float f) {
  union { float f; unsigned u; } v; v.f = f;
  unsigned r = v.u + 0x7fffu + ((v.u >> 16) & 1u);
  return (unsigned short)(r >> 16);
}
__device__ inline float bf2f(unsigned short u) {
  return __uint_as_float(((unsigned)u) << 16);
}
__device__ inline float exp2_fast(float x) {
  float r; asm("v_exp_f32 %0, %1" : "=v"(r) : "v"(x)); return r;
}
__device__ inline unsigned cvt_pk_bf16(float lo, float hi) {
  unsigned r; asm("v_cvt_pk_bf16_f32 %0, %1, %2" : "=v"(r) : "v"(lo), "v"(hi)); return r;
}
// a <- [a.l0-31 | b.l0-31], b <- [a.l32-63 | b.l32-63]
__device__ inline void permlane32_swap(unsigned& a, unsigned& b) {
  asm volatile("v_permlane32_swap_b32 %0, %1" : "+v"(a), "+v"(b));
}
__device__ inline void gll16(const unsigned short* src, void* lds) {
  __builtin_amdgcn_global_load_lds((const __attribute__((address_space(1))) void*)src,
                                   (__attribute__((address_space(3))) void*)lds, 16, 0, 0);
}

// wf layout (fragment-major): B-frag for (col-tile ct, k-step s) of the 320x256
// combined weight: element (col C = ct*16+cl, k = s*32+gf*8+j) lives at
// wf[((ct*8+s)*64 + gf*16+cl)*8 + j]. A wave's B-load = 64 lanes x 16B contiguous.
__device__ inline size_t wf_addr(int C, int kk) {
  int ct = C >> 4, cl = C & 15, s = kk >> 5, gf = (kk >> 3) & 3, j = kk & 7;
  return ((size_t)((ct * 8 + s) * 64 + gf * 16 + cl)) * 8 + j;
}

// ---------------- kernel 0a: weight casts ----------------
// wf tiles 0-3 (cols 0-63): w_q^T*log2e | w_k^T, fragment-major. wv_b, woT_b plain.
__global__ __launch_bounds__(256) void prep_kernel(const float* __restrict__ wq,
                                                   const float* __restrict__ wk,
                                                   const float* __restrict__ wo,
                                                   const float* __restrict__ wv,
                                                   unsigned short* __restrict__ wf,
                                                   unsigned short* __restrict__ wv_b,
                                                   unsigned short* __restrict__ woT_b) {
  int i = blockIdx.x * 256 + threadIdx.x;  // total 147456
  if (i < 16384) {
    int C = i >> 8, kk = i & 255;
    float v = (C < 32) ? wq[kk * 32 + C] * LOG2E : wk[kk * 32 + (C - 32)];
    wf[wf_addr(C, kk)] = f2bf(v);
  } else if (i < 81920) {
    int j = i - 16384;
    wv_b[j] = f2bf(wv[j]);
  } else {
    int j = i - 81920;  // woT_b[e2][e] = wo[e][e2]
    int e2 = j >> 8, e = j & 255;
    woT_b[j] = f2bf(wo[e * 256 + e2]);
  }
}

// ---------------- kernel 0b: Wvo^T = Wo^T . Wv^T -> wf tiles 4-19 (fragment-major) --
__global__ __launch_bounds__(256) void prep2_kernel(const unsigned short* __restrict__ woT_b,
                                                    const unsigned short* __restrict__ wv_b,
                                                    unsigned short* __restrict__ wf) {
  const int lane = threadIdx.x & 63, w = threadIdx.x >> 6;
  const int g = lane >> 4, li = lane & 15;
  const int m0 = blockIdx.x * 64 + w * 16;
  const unsigned short* arow = woT_b + (size_t)(m0 + li) * 256 + (g << 3);
  const unsigned short* brow = wv_b + (size_t)li * 256 + (g << 3);
  f32x4 acc[16] = {};
  for (int kk = 0; kk < 256; kk += 32) {
    short8 a = *reinterpret_cast<const short8*>(arow + kk);
#pragma unroll
    for (int ct = 0; ct < 16; ++ct) {
      short8 bb = *reinterpret_cast<const short8*>(brow + (size_t)ct * 16 * 256 + kk);
      acc[ct] = __builtin_amdgcn_mfma_f32_16x16x32_bf16(a, bb, acc[ct], 0, 0, 0);
    }
  }
#pragma unroll
  for (int ct = 0; ct < 16; ++ct)
#pragma unroll
    for (int r = 0; r < 4; ++r) {
      const int C = 64 + m0 + (g << 2) + r;  // output col in combined W (>=64)
      const int kk = ct * 16 + li;
      wf[wf_addr(C, kk)] = f2bf(acc[ct][r]);
    }
}

// ---------------- kernel 1: fused QKVW projection ----------------
// grid 512 x 256; block = 64 rows x 320 cols. x staged ONCE in LDS (swizzled,
// 32KB); W read as fragment-major coalesced 1KB B-loads straight into registers,
// double-buffered (BA/BB), counted vmcnt(5). Wave = 64 rows x 80 cols: per step
// 4 A ds_reads + 5 B reg-loads + 20 MFMAs (ratio 4). ONE barrier total.
__global__ __launch_bounds__(256, 2) void qkv_kernel(const float* __restrict__ x,
                                                     const unsigned short* __restrict__ wf,
                                                     unsigned short* __restrict__ q,
                                                     unsigned short* __restrict__ k,
                                                     unsigned short* __restrict__ vwT) {
  __shared__ __align__(16) unsigned short xs[64 * 256];  // 32KB, swizzled
  const int tid = threadIdx.x;
  const int l = tid & 63, w = tid >> 6;
  const int bx = blockIdx.x;
  const int g = l >> 4, li = l & 15;
  const int m0 = bx * 64;

  const unsigned short* wfb = wf + (size_t)(w * 5) * 4096;  // wave's 5 col-tiles

  // ---- issue B prologue loads first (oldest in vm queue) ----
  short8 BA[5], BB[5];
#pragma unroll
  for (int c = 0; c < 5; ++c)
    BA[c] = *reinterpret_cast<const short8*>(wfb + ((size_t)(c * 8 + 0) * 64 + l) * 8);
#pragma unroll
  for (int c = 0; c < 5; ++c)
    BB[c] = *reinterpret_cast<const short8*>(wfb + ((size_t)(c * 8 + 1) * 64 + l) * 8);

  // ---- stage x[64][256] -> bf16 LDS (cvt waits drain everything; then barrier) ----
  {
    const int row = tid >> 2, qtr = tid & 3;
    const float* src = x + (size_t)(m0 + row) * 256 + qtr * 64;
    unsigned short* dstrow = xs + row * 256;
#pragma unroll
    for (int jj = 0; jj < 8; ++jj) {
      f32x4 a0 = *reinterpret_cast<const f32x4*>(src + jj * 8);
      f32x4 a1 = *reinterpret_cast<const f32x4*>(src + jj * 8 + 4);
      union { unsigned u[4]; ushort8 v; } P;
      P.u[0] = cvt_pk_bf16(a0[0], a0[1]); P.u[1] = cvt_pk_bf16(a0[2], a0[3]);
      P.u[2] = cvt_pk_bf16(a1[0], a1[1]); P.u[3] = cvt_pk_bf16(a1[2], a1[3]);
      const int blk = (qtr * 8 + jj) ^ (row & 7);
      *reinterpret_cast<ushort8*>(dstrow + blk * 8) = P.v;
    }
  }
  __syncthreads();  // xs ready; read-only hereafter (no more barriers)

  f32x4 acc[4][5] = {};

#define QSTEP(S, BV, WN, PREF)                                                       \
  {                                                                                  \
    asm volatile("s_waitcnt vmcnt(" WN ")" ::: "memory");                            \
    __builtin_amdgcn_sched_barrier(0);                                               \
    short8 a_[4];                                                                    \
    _Pragma("unroll") for (int mt = 0; mt < 4; ++mt) {                               \
      const int row = mt * 16 + li;                                                  \
      a_[mt] = *reinterpret_cast<const short8*>(                                     \
          xs + row * 256 + ((((S) * 4 + g) ^ (row & 7)) << 3));                      \
    }                                                                                \
    _Pragma("unroll") for (int mt = 0; mt < 4; ++mt)                                 \
        _Pragma("unroll") for (int c = 0; c < 5; ++c)                                \
            acc[mt][c] = __builtin_amdgcn_mfma_f32_16x16x32_bf16(a_[mt], BV[c],      \
                                                                 acc[mt][c], 0, 0, 0); \
    if (PREF) {                                                                      \
      _Pragma("unroll") for (int c = 0; c < 5; ++c)                                  \
          BV[c] = *reinterpret_cast<const short8*>(                                  \
              wfb + ((size_t)(c * 8 + (S) + 2) * 64 + l) * 8);                       \
    }                                                                                \
  }

  QSTEP(0, BA, "5", true)
  QSTEP(1, BB, "5", true)
  QSTEP(2, BA, "5", true)
  QSTEP(3, BB, "5", true)
  QSTEP(4, BA, "5", true)
  QSTEP(5, BB, "5", true)
  QSTEP(6, BA, "5", false)
  QSTEP(7, BB, "0", false)
#undef QSTEP

  // ---- stores: wave w owns col-tiles w*5..w*5+4 over rows m0..m0+63 ----
  const int bb_ = bx >> 6;
#pragma unroll
  for (int mt = 0; mt < 4; ++mt) {
    const int nloc = (bx & 63) * 64 + mt * 16 + (g << 2);
#pragma unroll
    for (int c = 0; c < 5; ++c) {
      const int Cg = w * 5 + c;
      if (Cg < 2) {        // q cols 0-31
        const int col = Cg * 16 + li;
#pragma unroll
        for (int r = 0; r < 4; ++r)
          q[((size_t)bb_ * N_ + nloc + r) * D_ + col] = f2bf(acc[mt][c][r]);
      } else if (Cg < 4) {  // k cols 0-31
        const int col = (Cg - 2) * 16 + li;
#pragma unroll
        for (int r = 0; r < 4; ++r)
          k[((size_t)bb_ * N_ + nloc + r) * D_ + col] = f2bf(acc[mt][c][r]);
      } else {              // vwT channel c = Cg*16+li-64
        const int vc = Cg * 16 + li - 64;
        union { unsigned u[2]; ushort4v v; } P;
        P.u[0] = cvt_pk_bf16(acc[mt][c][0], acc[mt][c][1]);
        P.u[1] = cvt_pk_bf16(acc[mt][c][2], acc[mt][c][3]);
        *reinterpret_cast<ushort4v*>(&vwT[((size_t)bb_ * C_ + vc) * N_ + nloc]) = P.v;
      }
    }
  }
}

// ---------------- kernel 2: flash attention (r12, frozen) ----
__global__ __launch_bounds__(256, 2) void flash_kernel(const unsigned short* __restrict__ q,
                                                       const unsigned short* __restrict__ k,
                                                       const unsigned short* __restrict__ vwT,
                                                       unsigned short* __restrict__ opart,
                                                       float* __restrict__ lsumpart) {
  __shared__ __align__(16) char smem[53248];  // V 3x16384 @0 | K 2x2048 @49152
  const int tid = threadIdx.x;
  const int l = tid & 63, w_ = tid >> 6;
  const int qg = w_ >> 1, ch = w_ & 1;
  const int blk = blockIdx.x;
  const int b = blk & 7;
  const int kvh = (blk >> 3) & 1;
  const int qt = blk >> 4;  // 0..31
  const int h = l >> 5, l31 = l & 31;

  const unsigned short* kb_ = k + (size_t)b * N_ * D_;
  const unsigned short* vb_ = vwT + (size_t)b * C_ * N_;

  const int qposb = qt * 128 + qg * 64;  // + qt2*32 + l31
  short8 qb[2][2];
#pragma unroll
  for (int qt2 = 0; qt2 < 2; ++qt2) {
    const size_t qoff = ((size_t)b * N_ + qposb + qt2 * 32 + l31) * D_ + h * 8;
    qb[qt2][0] = *reinterpret_cast<const short8*>(q + qoff);
    qb[qt2][1] = *reinterpret_cast<const short8*>(q + qoff + 16);
  }
  asm volatile("s_waitcnt vmcnt(0)" ::: "memory");  // clean vm counter before staging

  const int stg_row = l >> 2;
  const int stg_bk = ((l & 3) ^ ((l >> 3) & 3)) << 3;  // elems
  const int kvbase = kvh * 2048;

#define STAGE_V(BUF, KV0)                                                         \
  {                                                                               \
    char* vd = smem + (BUF) * 16384 + w_ * 4096;                                  \
    _Pragma("unroll") for (int t = 0; t < 4; ++t)                                 \
        gll16(vb_ + (size_t)(w_ * 64 + t * 16 + stg_row) * N_ + (KV0) + stg_bk,   \
              vd + t * 1024);                                                     \
  }
#define STAGE_K(BUF, KV0)                                                         \
  {                                                                               \
    if (w_ < 2)                                                                   \
      gll16(kb_ + (size_t)((KV0) + w_ * 16 + stg_row) * D_ + stg_bk,              \
            smem + 49152 + (BUF) * 2048 + w_ * 1024);                             \
  }

  f32x16 o[4][2] = {};  // [ct][qt2]: O^T (32c x 32q), c = ch*128 + ct*32
  float lsum[2] = {0.f, 0.f};
  const f32x16 z16 = {};

  STAGE_V(0, kvbase)
  STAGE_K(0, kvbase)
  STAGE_V(1, kvbase + 32)

  int cur = 0, nxt = 2;
  for (int i = 0; i < 64; ++i) {
    if (i < 63) { asm volatile("s_waitcnt vmcnt(4)" ::: "memory"); }
    else        { asm volatile("s_waitcnt vmcnt(0)" ::: "memory"); }
    __builtin_amdgcn_sched_barrier(0);
    __builtin_amdgcn_s_barrier();  // chunk i landed; all waves done with prev reads
    if (i < 63) STAGE_K((i + 1) & 1, kvbase + (i + 1) * 32)
    if (i < 62) STAGE_V(nxt, kvbase + (i + 2) * 32)
    const char* Vb = smem + cur * 16384;
    const char* Kb = smem + 49152 + (i & 1) * 2048;
    const int kkey = (l31 >> 1) & 3;
    short8 ka0 = *reinterpret_cast<const short8*>(Kb + l31 * 64 + (((0 + h) ^ kkey) << 4));
    short8 ka1 = *reinterpret_cast<const short8*>(Kb + l31 * 64 + (((2 + h) ^ kkey) << 4));
    f32x16 s0 = __builtin_amdgcn_mfma_f32_32x32x16_bf16(ka0, qb[0][0], z16, 0, 0, 0);
    s0 = __builtin_amdgcn_mfma_f32_32x32x16_bf16(ka1, qb[0][1], s0, 0, 0, 0);
    f32x16 s1 = __builtin_amdgcn_mfma_f32_32x32x16_bf16(ka0, qb[1][0], z16, 0, 0, 0);
    s1 = __builtin_amdgcn_mfma_f32_32x32x16_bf16(ka1, qb[1][1], s1, 0, 0, 0);
    short8 pf[2][2];
#pragma unroll
    for (int r = 0; r < 16; ++r) s0[r] = exp2_fast(s0[r]);
    if (ch == 0)
      lsum[0] += (((s0[0] + s0[1]) + (s0[2] + s0[3])) + ((s0[4] + s0[5]) + (s0[6] + s0[7]))) +
                 (((s0[8] + s0[9]) + (s0[10] + s0[11])) + ((s0[12] + s0[13]) + (s0[14] + s0[15])));
    {
      unsigned x0 = cvt_pk_bf16(s0[0], s0[1]),   y0 = cvt_pk_bf16(s0[4], s0[5]);
      unsigned x1 = cvt_pk_bf16(s0[2], s0[3]),   y1 = cvt_pk_bf16(s0[6], s0[7]);
      unsigned x2 = cvt_pk_bf16(s0[8], s0[9]),   y2 = cvt_pk_bf16(s0[12], s0[13]);
      unsigned x3 = cvt_pk_bf16(s0[10], s0[11]), y3 = cvt_pk_bf16(s0[14], s0[15]);
      permlane32_swap(x0, y0); permlane32_swap(x1, y1);
      permlane32_swap(x2, y2); permlane32_swap(x3, y3);
      union U { unsigned u[4]; short8 v; };
      U u0; u0.u[0] = x0; u0.u[1] = x1; u0.u[2] = y0; u0.u[3] = y1;  // kv 0-15
      U u1; u1.u[0] = x2; u1.u[1] = x3; u1.u[2] = y2; u1.u[3] = y3;  // kv 16-31
      pf[0][0] = u0.v; pf[0][1] = u1.v;
    }
#pragma unroll
    for (int r = 0; r < 16; ++r) s1[r] = exp2_fast(s1[r]);
    if (ch == 0)
      lsum[1] += (((s1[0] + s1[1]) + (s1[2] + s1[3])) + ((s1[4] + s1[5]) + (s1[6] + s1[7]))) +
                 (((s1[8] + s1[9]) + (s1[10] + s1[11])) + ((s1[12] + s1[13]) + (s1[14] + s1[15])));
    {
      unsigned x0 = cvt_pk_bf16(s1[0], s1[1]),   y0 = cvt_pk_bf16(s1[4], s1[5]);
      unsigned x1 = cvt_pk_bf16(s1[2], s1[3]),   y1 = cvt_pk_bf16(s1[6], s1[7]);
      unsigned x2 = cvt_pk_bf16(s1[8], s1[9]),   y2 = cvt_pk_bf16(s1[12], s1[13]);
      unsigned x3 = cvt_pk_bf16(s1[10], s1[11]), y3 = cvt_pk_bf16(s1[14], s1[15]);
      permlane32_swap(x0, y0); permlane32_swap(x1, y1);
      permlane32_swap(x2, y2); permlane32_swap(x3, y3);
      union U { unsigned u[4]; short8 v; };
      U u0; u0.u[0] = x0; u0.u[1] = x1; u0.u[2] = y0; u0.u[3] = y1;
      U u1; u1.u[0] = x2; u1.u[1] = x3; u1.u[2] = y2; u1.u[3] = y3;
      pf[1][0] = u0.v; pf[1][1] = u1.v;
    }
    __builtin_amdgcn_s_setprio(1);
#pragma unroll
    for (int ct = 0; ct < 4; ++ct) {
      const int rl = ch * 128 + ct * 32 + l31;
      const int vkey = (rl >> 1) & 3;
      short8 va0 = *reinterpret_cast<const short8*>(Vb + rl * 64 + (((0 + h) ^ vkey) << 4));
      short8 va1 = *reinterpret_cast<const short8*>(Vb + rl * 64 + (((2 + h) ^ vkey) << 4));
      o[ct][0] = __builtin_amdgcn_mfma_f32_32x32x16_bf16(va0, pf[0][0], o[ct][0], 0, 0, 0);
      o[ct][0] = __builtin_amdgcn_mfma_f32_32x32x16_bf16(va1, pf[0][1], o[ct][0], 0, 0, 0);
      o[ct][1] = __builtin_amdgcn_mfma_f32_32x32x16_bf16(va0, pf[1][0], o[ct][1], 0, 0, 0);
      o[ct][1] = __builtin_amdgcn_mfma_f32_32x32x16_bf16(va1, pf[1][1], o[ct][1], 0, 0, 0);
    }
    __builtin_amdgcn_s_setprio(0);
    cur = (cur == 2) ? 0 : cur + 1;
    nxt = (nxt == 2) ? 0 : nxt + 1;
  }

  lsum[0] += __shfl_xor(lsum[0], 32);
  lsum[1] += __shfl_xor(lsum[1], 32);
  unsigned short* op = opart + ((size_t)kvh * B_ + b) * (size_t)N_ * C_;
#pragma unroll
  for (int qt2 = 0; qt2 < 2; ++qt2) {
    const size_t rowoff = (size_t)(qposb + qt2 * 32 + l31) * C_ + ch * 128;
#pragma unroll
    for (int ct = 0; ct < 4; ++ct)
#pragma unroll
      for (int j = 0; j < 8; ++j) {
        const int c = ct * 32 + 2 * (j & 1) + 8 * (j >> 1) + 4 * h;
        unsigned wv = cvt_pk_bf16(o[ct][qt2][2 * j], o[ct][qt2][2 * j + 1]);
        *reinterpret_cast<unsigned*>(&op[rowoff + c]) = wv;
      }
  }
  if (h == 0 && ch == 0) {
    float* lp = lsumpart + ((size_t)kvh * B_ + b) * N_ + qposb;
    lp[l31] = lsum[0];
    lp[32 + l31] = lsum[1];
  }
#undef STAGE_V
#undef STAGE_K
}

// ---------------- kernel 3: merge kv-split partials + residual (grid-strided) ------
__global__ __launch_bounds__(256) void merge_kernel(const unsigned short* __restrict__ opart,
                                                    const float* __restrict__ lsumpart,
                                                    const float* __restrict__ x,
                                                    float* __restrict__ out) {
  const int base = blockIdx.x * 256 + threadIdx.x;
#pragma unroll
  for (int kk = 0; kk < 4; ++kk) {
    const int i4 = base + kk * 524288;  // f32x4 group, total 2097152
    const int m = i4 >> 6;              // row (64 groups per 256-c row)
    const float inv = 1.0f / (lsumpart[m] + lsumpart[B_ * N_ + m]);
    ushort4v a0 = *reinterpret_cast<const ushort4v*>(opart + (size_t)i4 * 4);
    ushort4v a1 = *reinterpret_cast<const ushort4v*>(opart + (size_t)B_ * N_ * C_ + (size_t)i4 * 4);
    f32x4 xr = *reinterpret_cast<const f32x4*>(x + (size_t)i4 * 4);
    f32x4 t;
    t[0] = xr[0] + (bf2f(a0[0]) + bf2f(a1[0])) * inv;
    t[1] = xr[1] + (bf2f(a0[1]) + bf2f(a1[1])) * inv;
    t[2] = xr[2] + (bf2f(a0[2]) + bf2f(a1[2])) * inv;
    t[3] = xr[3] + (bf2f(a0[3]) + bf2f(a1[3])) * inv;
    *reinterpret_cast<f32x4*>(out + (size_t)i4 * 4) = t;
  }
}

extern "C" void kernel_launch(void* const* d_in, const int* in_sizes, int n_in,
                              void* d_out, int out_size, void* d_ws, size_t ws_size,
                              hipStream_t stream) {
  const float* x  = (const float*)d_in[0];
  const float* wq = (const float*)d_in[1];
  const float* wk = (const float*)d_in[2];
  const float* wv = (const float*)d_in[3];
  const float* wo = (const float*)d_in[4];
  float* out = (float*)d_out;
  char* ws = (char*)d_ws;
  unsigned short* wf    = (unsigned short*)(ws + 0);         // 163840 B (frag-major W)
  unsigned short* wv_b  = (unsigned short*)(ws + 163840);    // 131072 B
  unsigned short* woT_b = (unsigned short*)(ws + 294912);    // 131072 B
  unsigned short* q     = (unsigned short*)(ws + 425984);    // 2 MB
  unsigned short* k     = (unsigned short*)(ws + 2523136);   // 2 MB
  unsigned short* vwT   = (unsigned short*)(ws + 4620288);   // 16 MB
  unsigned short* opart = (unsigned short*)(ws + 21397504);  // 32 MB (2 parts)
  float*          lsump = (float*)(ws + 54951936);           // 256 KB (total ~55.2 MB)

  prep_kernel<<<576, 256, 0, stream>>>(wq, wk, wo, wv, wf, wv_b, woT_b);
  prep2_kernel<<<4, 256, 0, stream>>>(woT_b, wv_b, wf);
  qkv_kernel<<<512, 256, 0, stream>>>(x, wf, q, k, vwT);
  flash_kernel<<<512, 256, 0, stream>>>(q, k, vwT, opart, lsump);
  merge_kernel<<<2048, 256, 0, stream>>>(opart, lsump, x, out);
}

// Round 14
// 139.542 us; speedup vs baseline: 1.2995x; 1.1004x over previous
//
#include <hip/hip_runtime.h>
#include <hip/hip_bf16.h>
#include <stdint.h>

typedef __attribute__((ext_vector_type(8))) short short8;
typedef __attribute__((ext_vector_type(8))) unsigned short ushort8;
typedef __attribute__((ext_vector_type(4))) unsigned short ushort4v;
typedef __attribute__((ext_vector_type(4))) unsigned u32x4;
typedef __attribute__((ext_vector_type(2))) float f32x2;
typedef __attribute__((ext_vector_type(4))) float f32x4;
typedef __attribute__((ext_vector_type(16))) float f32x16;

#define B_ 8
#define N_ 4096
#define C_ 256
#define D_ 32
#define LOG2E 1.44269504088896f

__device__ inline unsigned short f2bf(float f) {
  union { float f; unsigned u; } v; v.f = f;
  unsigned r = v.u + 0x7fffu + ((v.u >> 16) & 1u);
  return (unsigned short)(r >> 16);
}
__device__ inline float bf2f(unsigned short u) {
  return __uint_as_float(((unsigned)u) << 16);
}
__device__ inline float exp2_fast(float x) {
  float r; asm("v_exp_f32 %0, %1" : "=v"(r) : "v"(x)); return r;
}
__device__ inline unsigned cvt_pk_bf16(float lo, float hi) {
  unsigned r; asm("v_cvt_pk_bf16_f32 %0, %1, %2" : "=v"(r) : "v"(lo), "v"(hi)); return r;
}
// a <- [a.l0-31 | b.l0-31], b <- [a.l32-63 | b.l32-63]
__device__ inline void permlane32_swap(unsigned& a, unsigned& b) {
  asm volatile("v_permlane32_swap_b32 %0, %1" : "+v"(a), "+v"(b));
}
__device__ inline void gll16(const unsigned short* src, void* lds) {
  __builtin_amdgcn_global_load_lds((const __attribute__((address_space(1))) void*)src,
                                   (__attribute__((address_space(3))) void*)lds, 16, 0, 0);
}

// wf layout (fragment-major): B-frag for (col-tile ct, k-step s) of the 320x256
// combined weight: element (col C = ct*16+cl, k = s*32+gf*8+j) lives at
// wf[((ct*8+s)*64 + gf*16+cl)*8 + j]. A wave's B-load = 64 lanes x 16B contiguous.
__device__ inline size_t wf_addr(int C, int kk) {
  int ct = C >> 4, cl = C & 15, s = kk >> 5, gf = (kk >> 3) & 3, j = kk & 7;
  return ((size_t)((ct * 8 + s) * 64 + gf * 16 + cl)) * 8 + j;
}

// ---------------- kernel 0a: weight casts ----------------
__global__ __launch_bounds__(256) void prep_kernel(const float* __restrict__ wq,
                                                   const float* __restrict__ wk,
                                                   const float* __restrict__ wo,
                                                   const float* __restrict__ wv,
                                                   unsigned short* __restrict__ wf,
                                                   unsigned short* __restrict__ wv_b,
                                                   unsigned short* __restrict__ woT_b) {
  int i = blockIdx.x * 256 + threadIdx.x;  // total 147456
  if (i < 16384) {
    int C = i >> 8, kk = i & 255;
    float v = (C < 32) ? wq[kk * 32 + C] * LOG2E : wk[kk * 32 + (C - 32)];
    wf[wf_addr(C, kk)] = f2bf(v);
  } else if (i < 81920) {
    int j = i - 16384;
    wv_b[j] = f2bf(wv[j]);
  } else {
    int j = i - 81920;  // woT_b[e2][e] = wo[e][e2]
    int e2 = j >> 8, e = j & 255;
    woT_b[j] = f2bf(wo[e * 256 + e2]);
  }
}

// ---------------- kernel 0b: Wvo^T = Wo^T . Wv^T -> wf tiles 4-19 (fragment-major) --
__global__ __launch_bounds__(256) void prep2_kernel(const unsigned short* __restrict__ woT_b,
                                                    const unsigned short* __restrict__ wv_b,
                                                    unsigned short* __restrict__ wf) {
  const int lane = threadIdx.x & 63, w = threadIdx.x >> 6;
  const int g = lane >> 4, li = lane & 15;
  const int m0 = blockIdx.x * 64 + w * 16;
  const unsigned short* arow = woT_b + (size_t)(m0 + li) * 256 + (g << 3);
  const unsigned short* brow = wv_b + (size_t)li * 256 + (g << 3);
  f32x4 acc[16] = {};
  for (int kk = 0; kk < 256; kk += 32) {
    short8 a = *reinterpret_cast<const short8*>(arow + kk);
#pragma unroll
    for (int ct = 0; ct < 16; ++ct) {
      short8 bb = *reinterpret_cast<const short8*>(brow + (size_t)ct * 16 * 256 + kk);
      acc[ct] = __builtin_amdgcn_mfma_f32_16x16x32_bf16(a, bb, acc[ct], 0, 0, 0);
    }
  }
#pragma unroll
  for (int ct = 0; ct < 16; ++ct)
#pragma unroll
    for (int r = 0; r < 4; ++r) {
      const int C = 64 + m0 + (g << 2) + r;
      const int kk = ct * 16 + li;
      wf[wf_addr(C, kk)] = f2bf(acc[ct][r]);
    }
}

// ---------------- kernel 1: fused QKVW projection (r13, validated) ----------------
__global__ __launch_bounds__(256, 2) void qkv_kernel(const float* __restrict__ x,
                                                     const unsigned short* __restrict__ wf,
                                                     unsigned short* __restrict__ q,
                                                     unsigned short* __restrict__ k,
                                                     unsigned short* __restrict__ vwT) {
  __shared__ __align__(16) unsigned short xs[64 * 256];  // 32KB, swizzled
  const int tid = threadIdx.x;
  const int l = tid & 63, w = tid >> 6;
  const int bx = blockIdx.x;
  const int g = l >> 4, li = l & 15;
  const int m0 = bx * 64;

  const unsigned short* wfb = wf + (size_t)(w * 5) * 4096;  // wave's 5 col-tiles

  short8 BA[5], BB[5];
#pragma unroll
  for (int c = 0; c < 5; ++c)
    BA[c] = *reinterpret_cast<const short8*>(wfb + ((size_t)(c * 8 + 0) * 64 + l) * 8);
#pragma unroll
  for (int c = 0; c < 5; ++c)
    BB[c] = *reinterpret_cast<const short8*>(wfb + ((size_t)(c * 8 + 1) * 64 + l) * 8);

  {
    const int row = tid >> 2, qtr = tid & 3;
    const float* src = x + (size_t)(m0 + row) * 256 + qtr * 64;
    unsigned short* dstrow = xs + row * 256;
#pragma unroll
    for (int jj = 0; jj < 8; ++jj) {
      f32x4 a0 = *reinterpret_cast<const f32x4*>(src + jj * 8);
      f32x4 a1 = *reinterpret_cast<const f32x4*>(src + jj * 8 + 4);
      union { unsigned u[4]; ushort8 v; } P;
      P.u[0] = cvt_pk_bf16(a0[0], a0[1]); P.u[1] = cvt_pk_bf16(a0[2], a0[3]);
      P.u[2] = cvt_pk_bf16(a1[0], a1[1]); P.u[3] = cvt_pk_bf16(a1[2], a1[3]);
      const int blk = (qtr * 8 + jj) ^ (row & 7);
      *reinterpret_cast<ushort8*>(dstrow + blk * 8) = P.v;
    }
  }
  __syncthreads();  // xs ready; read-only hereafter

  f32x4 acc[4][5] = {};

#define QSTEP(S, BV, WN, PREF)                                                       \
  {                                                                                  \
    asm volatile("s_waitcnt vmcnt(" WN ")" ::: "memory");                            \
    __builtin_amdgcn_sched_barrier(0);                                               \
    short8 a_[4];                                                                    \
    _Pragma("unroll") for (int mt = 0; mt < 4; ++mt) {                               \
      const int row = mt * 16 + li;                                                  \
      a_[mt] = *reinterpret_cast<const short8*>(                                     \
          xs + row * 256 + ((((S) * 4 + g) ^ (row & 7)) << 3));                      \
    }                                                                                \
    _Pragma("unroll") for (int mt = 0; mt < 4; ++mt)                                 \
        _Pragma("unroll") for (int c = 0; c < 5; ++c)                                \
            acc[mt][c] = __builtin_amdgcn_mfma_f32_16x16x32_bf16(a_[mt], BV[c],      \
                                                                 acc[mt][c], 0, 0, 0); \
    if (PREF) {                                                                      \
      _Pragma("unroll") for (int c = 0; c < 5; ++c)                                  \
          BV[c] = *reinterpret_cast<const short8*>(                                  \
              wfb + ((size_t)(c * 8 + (S) + 2) * 64 + l) * 8);                       \
    }                                                                                \
  }

  QSTEP(0, BA, "5", true)
  QSTEP(1, BB, "5", true)
  QSTEP(2, BA, "5", true)
  QSTEP(3, BB, "5", true)
  QSTEP(4, BA, "5", true)
  QSTEP(5, BB, "5", true)
  QSTEP(6, BA, "5", false)
  QSTEP(7, BB, "0", false)
#undef QSTEP

  const int bb_ = bx >> 6;
#pragma unroll
  for (int mt = 0; mt < 4; ++mt) {
    const int nloc = (bx & 63) * 64 + mt * 16 + (g << 2);
#pragma unroll
    for (int c = 0; c < 5; ++c) {
      const int Cg = w * 5 + c;
      if (Cg < 2) {
        const int col = Cg * 16 + li;
#pragma unroll
        for (int r = 0; r < 4; ++r)
          q[((size_t)bb_ * N_ + nloc + r) * D_ + col] = f2bf(acc[mt][c][r]);
      } else if (Cg < 4) {
        const int col = (Cg - 2) * 16 + li;
#pragma unroll
        for (int r = 0; r < 4; ++r)
          k[((size_t)bb_ * N_ + nloc + r) * D_ + col] = f2bf(acc[mt][c][r]);
      } else {
        const int vc = Cg * 16 + li - 64;
        union { unsigned u[2]; ushort4v v; } P;
        P.u[0] = cvt_pk_bf16(acc[mt][c][0], acc[mt][c][1]);
        P.u[1] = cvt_pk_bf16(acc[mt][c][2], acc[mt][c][3]);
        *reinterpret_cast<ushort4v*>(&vwT[((size_t)bb_ * C_ + vc) * N_ + nloc]) = P.v;
      }
    }
  }
}

// ---------------- kernel 2: flash attention, kv-halves fused in one block ----------
// grid 256 x 512. blk: b = blk&7 (XCD pin: batch b -> XCD b, 32 blocks = 32 CUs),
// qt = blk>>3 (0..31). 8 waves: kvh = w>>2 (2048-kv half), gw = w&3 -> qg = gw>>1,
// ch = gw&1. Each 4-wave kvh-group runs the r12-proven loop in its own 53KB LDS
// region (V 3x16KB 2-ahead + K 2x2KB 1-ahead, uniform vmcnt(4), one s_barrier per
// chunk -- barrier couples both groups, which do identical work). 106KB LDS ->
// 1 block/CU = 8 waves/CU = 2/SIMD (same as r12). After the loop the kv-halves
// are merged IN-BLOCK via LDS (bf16 pairs, conflict-free b128 lane-major slots),
// normalized, x residual added, final fp32 out written. No merge kernel, no opart.
__global__ __launch_bounds__(512, 2) void flash_kernel(const unsigned short* __restrict__ q,
                                                       const unsigned short* __restrict__ k,
                                                       const unsigned short* __restrict__ vwT,
                                                       const float* __restrict__ x,
                                                       float* __restrict__ out) {
  __shared__ __align__(16) char smem[106496];  // per kvh: V 3x16384 | K 2x2048
  const int tid = threadIdx.x;
  const int l = tid & 63, w_ = tid >> 6;       // 0..7
  const int kvh = w_ >> 2, gw = w_ & 3;
  const int qg = gw >> 1, ch = gw & 1;
  const int blk = blockIdx.x;
  const int b = blk & 7;
  const int qt = blk >> 3;                     // 0..31
  const int h = l >> 5, l31 = l & 31;
  const int R = kvh * 53248;

  const unsigned short* kb_ = k + (size_t)b * N_ * D_;
  const unsigned short* vb_ = vwT + (size_t)b * C_ * N_;

  // Q B-frags qb[qt2][ks]: col q = l31, k-dim = ks*16 + 8h + j
  const int qposb = qt * 128 + qg * 64;  // + qt2*32 + l31
  short8 qb[2][2];
#pragma unroll
  for (int qt2 = 0; qt2 < 2; ++qt2) {
    const size_t qoff = ((size_t)b * N_ + qposb + qt2 * 32 + l31) * D_ + h * 8;
    qb[qt2][0] = *reinterpret_cast<const short8*>(q + qoff);
    qb[qt2][1] = *reinterpret_cast<const short8*>(q + qoff + 16);
  }
  asm volatile("s_waitcnt vmcnt(0)" ::: "memory");  // clean vm counter before staging

  const int stg_row = l >> 2;
  const int stg_bk = ((l & 3) ^ ((l >> 3) & 3)) << 3;  // elems
  const int kvbase = kvh * 2048;

  // group wave gw stages V rows gw*64..+63 (4 gll16); gw 0,1 stage 16 K rows each.
#define STAGE_V(BUF, KV0)                                                         \
  {                                                                               \
    char* vd = smem + R + (BUF) * 16384 + gw * 4096;                              \
    _Pragma("unroll") for (int t = 0; t < 4; ++t)                                 \
        gll16(vb_ + (size_t)(gw * 64 + t * 16 + stg_row) * N_ + (KV0) + stg_bk,   \
              vd + t * 1024);                                                     \
  }
#define STAGE_K(BUF, KV0)                                                         \
  {                                                                               \
    if (gw < 2)                                                                   \
      gll16(kb_ + (size_t)((KV0) + gw * 16 + stg_row) * D_ + stg_bk,              \
            smem + R + 49152 + (BUF) * 2048 + gw * 1024);                         \
  }

  f32x16 o[4][2] = {};  // [ct][qt2]: O^T (32c x 32q), c = ch*128 + ct*32
  float lsum[2] = {0.f, 0.f};
  const f32x16 z16 = {};

  // prologue: V(0), K(0), V(1)  -> first-iter vmcnt(4) drains V(0)+K(0)
  STAGE_V(0, kvbase)
  STAGE_K(0, kvbase)
  STAGE_V(1, kvbase + 32)

  int cur = 0, nxt = 2;
  for (int i = 0; i < 64; ++i) {
    if (i < 63) { asm volatile("s_waitcnt vmcnt(4)" ::: "memory"); }
    else        { asm volatile("s_waitcnt vmcnt(0)" ::: "memory"); }
    __builtin_amdgcn_sched_barrier(0);
    __builtin_amdgcn_s_barrier();  // chunk i landed; all waves done with prev reads
    if (i < 63) STAGE_K((i + 1) & 1, kvbase + (i + 1) * 32)
    if (i < 62) STAGE_V(nxt, kvbase + (i + 2) * 32)
    const char* Vb = smem + R + cur * 16384;
    const char* Kb = smem + R + 49152 + (i & 1) * 2048;
    // ---- both S^T = K.Q^T pairs back-to-back ----
    const int kkey = (l31 >> 1) & 3;
    short8 ka0 = *reinterpret_cast<const short8*>(Kb + l31 * 64 + (((0 + h) ^ kkey) << 4));
    short8 ka1 = *reinterpret_cast<const short8*>(Kb + l31 * 64 + (((2 + h) ^ kkey) << 4));
    f32x16 s0 = __builtin_amdgcn_mfma_f32_32x32x16_bf16(ka0, qb[0][0], z16, 0, 0, 0);
    s0 = __builtin_amdgcn_mfma_f32_32x32x16_bf16(ka1, qb[0][1], s0, 0, 0, 0);
    f32x16 s1 = __builtin_amdgcn_mfma_f32_32x32x16_bf16(ka0, qb[1][0], z16, 0, 0, 0);
    s1 = __builtin_amdgcn_mfma_f32_32x32x16_bf16(ka1, qb[1][1], s1, 0, 0, 0);
    short8 pf[2][2];
#pragma unroll
    for (int r = 0; r < 16; ++r) s0[r] = exp2_fast(s0[r]);
    if (ch == 0)
      lsum[0] += (((s0[0] + s0[1]) + (s0[2] + s0[3])) + ((s0[4] + s0[5]) + (s0[6] + s0[7]))) +
                 (((s0[8] + s0[9]) + (s0[10] + s0[11])) + ((s0[12] + s0[13]) + (s0[14] + s0[15])));
    {
      unsigned x0 = cvt_pk_bf16(s0[0], s0[1]),   y0 = cvt_pk_bf16(s0[4], s0[5]);
      unsigned x1 = cvt_pk_bf16(s0[2], s0[3]),   y1 = cvt_pk_bf16(s0[6], s0[7]);
      unsigned x2 = cvt_pk_bf16(s0[8], s0[9]),   y2 = cvt_pk_bf16(s0[12], s0[13]);
      unsigned x3 = cvt_pk_bf16(s0[10], s0[11]), y3 = cvt_pk_bf16(s0[14], s0[15]);
      permlane32_swap(x0, y0); permlane32_swap(x1, y1);
      permlane32_swap(x2, y2); permlane32_swap(x3, y3);
      union U { unsigned u[4]; short8 v; };
      U u0; u0.u[0] = x0; u0.u[1] = x1; u0.u[2] = y0; u0.u[3] = y1;  // kv 0-15
      U u1; u1.u[0] = x2; u1.u[1] = x3; u1.u[2] = y2; u1.u[3] = y3;  // kv 16-31
      pf[0][0] = u0.v; pf[0][1] = u1.v;
    }
#pragma unroll
    for (int r = 0; r < 16; ++r) s1[r] = exp2_fast(s1[r]);
    if (ch == 0)
      lsum[1] += (((s1[0] + s1[1]) + (s1[2] + s1[3])) + ((s1[4] + s1[5]) + (s1[6] + s1[7]))) +
                 (((s1[8] + s1[9]) + (s1[10] + s1[11])) + ((s1[12] + s1[13]) + (s1[14] + s1[15])));
    {
      unsigned x0 = cvt_pk_bf16(s1[0], s1[1]),   y0 = cvt_pk_bf16(s1[4], s1[5]);
      unsigned x1 = cvt_pk_bf16(s1[2], s1[3]),   y1 = cvt_pk_bf16(s1[6], s1[7]);
      unsigned x2 = cvt_pk_bf16(s1[8], s1[9]),   y2 = cvt_pk_bf16(s1[12], s1[13]);
      unsigned x3 = cvt_pk_bf16(s1[10], s1[11]), y3 = cvt_pk_bf16(s1[14], s1[15]);
      permlane32_swap(x0, y0); permlane32_swap(x1, y1);
      permlane32_swap(x2, y2); permlane32_swap(x3, y3);
      union U { unsigned u[4]; short8 v; };
      U u0; u0.u[0] = x0; u0.u[1] = x1; u0.u[2] = y0; u0.u[3] = y1;
      U u1; u1.u[0] = x2; u1.u[1] = x3; u1.u[2] = y2; u1.u[3] = y3;
      pf[1][0] = u0.v; pf[1][1] = u1.v;
    }
    // ---- PV: O^T[c][q] += V^T . P^T (va feeds both qt2) ----
    __builtin_amdgcn_s_setprio(1);
#pragma unroll
    for (int ct = 0; ct < 4; ++ct) {
      const int rl = ch * 128 + ct * 32 + l31;
      const int vkey = (rl >> 1) & 3;
      short8 va0 = *reinterpret_cast<const short8*>(Vb + rl * 64 + (((0 + h) ^ vkey) << 4));
      short8 va1 = *reinterpret_cast<const short8*>(Vb + rl * 64 + (((2 + h) ^ vkey) << 4));
      o[ct][0] = __builtin_amdgcn_mfma_f32_32x32x16_bf16(va0, pf[0][0], o[ct][0], 0, 0, 0);
      o[ct][0] = __builtin_amdgcn_mfma_f32_32x32x16_bf16(va1, pf[0][1], o[ct][0], 0, 0, 0);
      o[ct][1] = __builtin_amdgcn_mfma_f32_32x32x16_bf16(va0, pf[1][0], o[ct][1], 0, 0, 0);
      o[ct][1] = __builtin_amdgcn_mfma_f32_32x32x16_bf16(va1, pf[1][1], o[ct][1], 0, 0, 0);
    }
    __builtin_amdgcn_s_setprio(0);
    cur = (cur == 2) ? 0 : cur + 1;
    nxt = (nxt == 2) ? 0 : nxt + 1;
  }

  // ---- in-block kv-merge + normalize + residual + final store ----
  lsum[0] += __shfl_xor(lsum[0], 32);
  lsum[1] += __shfl_xor(lsum[1], 32);
  __syncthreads();  // final chunk reads complete; LDS reusable
  float* lb = reinterpret_cast<float*>(smem + 65536);  // lsums[2][2][64]
  if (ch == 0 && h == 0) {
    lb[kvh * 128 + qg * 64 + l31] = lsum[0];
    lb[kvh * 128 + qg * 64 + 32 + l31] = lsum[1];
  }
  if (kvh == 1) {
    char* ob = smem + gw * 16384;  // wave slot: 64 bf16-pairs/lane, b128 lane-major
    int pg = 0;
#pragma unroll
    for (int ct = 0; ct < 4; ++ct)
#pragma unroll
      for (int qt2 = 0; qt2 < 2; ++qt2)
#pragma unroll
        for (int jg = 0; jg < 2; ++jg) {
          u32x4 t;
#pragma unroll
          for (int e = 0; e < 4; ++e) {
            const int j = jg * 4 + e;
            t[e] = cvt_pk_bf16(o[ct][qt2][2 * j], o[ct][qt2][2 * j + 1]);
          }
          *reinterpret_cast<u32x4*>(ob + pg * 1024 + l * 16) = t;
          ++pg;
        }
  }
  __syncthreads();
  if (kvh == 0) {
    float inv[2];
#pragma unroll
    for (int qt2 = 0; qt2 < 2; ++qt2)
      inv[qt2] = 1.0f / (lb[qg * 64 + qt2 * 32 + l31] + lb[128 + qg * 64 + qt2 * 32 + l31]);
    const char* ob = smem + gw * 16384;
    int pg = 0;
#pragma unroll
    for (int ct = 0; ct < 4; ++ct)
#pragma unroll
      for (int qt2 = 0; qt2 < 2; ++qt2)
#pragma unroll
        for (int jg = 0; jg < 2; ++jg) {
          u32x4 t = *reinterpret_cast<const u32x4*>(ob + pg * 1024 + l * 16);
          ++pg;
#pragma unroll
          for (int e = 0; e < 4; ++e) {
            const int j = jg * 4 + e;
            o[ct][qt2][2 * j]     += bf2f((unsigned short)(t[e] & 0xffffu));
            o[ct][qt2][2 * j + 1] += bf2f((unsigned short)(t[e] >> 16));
          }
        }
#pragma unroll
    for (int qt2 = 0; qt2 < 2; ++qt2) {
      const size_t rowbase = ((size_t)b * N_ + qposb + qt2 * 32 + l31) * C_ + ch * 128;
#pragma unroll
      for (int ct = 0; ct < 4; ++ct)
#pragma unroll
        for (int j = 0; j < 8; ++j) {
          const int c = ct * 32 + 2 * (j & 1) + 8 * (j >> 1) + 4 * h;
          f32x2 xr = *reinterpret_cast<const f32x2*>(x + rowbase + c);
          f32x2 t;
          t[0] = o[ct][qt2][2 * j] * inv[qt2] + xr[0];
          t[1] = o[ct][qt2][2 * j + 1] * inv[qt2] + xr[1];
          *reinterpret_cast<f32x2*>(out + rowbase + c) = t;
        }
    }
  }
#undef STAGE_V
#undef STAGE_K
}

extern "C" void kernel_launch(void* const* d_in, const int* in_sizes, int n_in,
                              void* d_out, int out_size, void* d_ws, size_t ws_size,
                              hipStream_t stream) {
  const float* x  = (const float*)d_in[0];
  const float* wq = (const float*)d_in[1];
  const float* wk = (const float*)d_in[2];
  const float* wv = (const float*)d_in[3];
  const float* wo = (const float*)d_in[4];
  float* out = (float*)d_out;
  char* ws = (char*)d_ws;
  unsigned short* wf    = (unsigned short*)(ws + 0);         // 163840 B (frag-major W)
  unsigned short* wv_b  = (unsigned short*)(ws + 163840);    // 131072 B
  unsigned short* woT_b = (unsigned short*)(ws + 294912);    // 131072 B
  unsigned short* q     = (unsigned short*)(ws + 425984);    // 2 MB
  unsigned short* k     = (unsigned short*)(ws + 2523136);   // 2 MB
  unsigned short* vwT   = (unsigned short*)(ws + 4620288);   // 16 MB (total ~20.4 MB)

  prep_kernel<<<576, 256, 0, stream>>>(wq, wk, wo, wv, wf, wv_b, woT_b);
  prep2_kernel<<<4, 256, 0, stream>>>(woT_b, wv_b, wf);
  qkv_kernel<<<512, 256, 0, stream>>>(x, wf, q, k, vwT);
  flash_kernel<<<256, 512, 0, stream>>>(q, k, vwT, x, out);
}

// Round 15
// 135.724 us; speedup vs baseline: 1.3360x; 1.0281x over previous
//
#include <hip/hip_runtime.h>
#include <hip/hip_bf16.h>
#include <stdint.h>

typedef __attribute__((ext_vector_type(8))) short short8;
typedef __attribute__((ext_vector_type(8))) unsigned short ushort8;
typedef __attribute__((ext_vector_type(4))) unsigned short ushort4v;
typedef __attribute__((ext_vector_type(4))) unsigned u32x4;
typedef __attribute__((ext_vector_type(2))) float f32x2;
typedef __attribute__((ext_vector_type(4))) float f32x4;
typedef __attribute__((ext_vector_type(16))) float f32x16;

#define B_ 8
#define N_ 4096
#define C_ 256
#define D_ 32
#define LOG2E 1.44269504088896f

__device__ inline unsigned short f2bf(float f) {
  union { float f; unsigned u; } v; v.f = f;
  unsigned r = v.u + 0x7fffu + ((v.u >> 16) & 1u);
  return (unsigned short)(r >> 16);
}
__device__ inline float bf2f(unsigned short u) {
  return __uint_as_float(((unsigned)u) << 16);
}
__device__ inline float exp2_fast(float x) {
  float r; asm("v_exp_f32 %0, %1" : "=v"(r) : "v"(x)); return r;
}
__device__ inline unsigned cvt_pk_bf16(float lo, float hi) {
  unsigned r; asm("v_cvt_pk_bf16_f32 %0, %1, %2" : "=v"(r) : "v"(lo), "v"(hi)); return r;
}
// a <- [a.l0-31 | b.l0-31], b <- [a.l32-63 | b.l32-63]
__device__ inline void permlane32_swap(unsigned& a, unsigned& b) {
  asm volatile("v_permlane32_swap_b32 %0, %1" : "+v"(a), "+v"(b));
}
__device__ inline void gll16(const unsigned short* src, void* lds) {
  __builtin_amdgcn_global_load_lds((const __attribute__((address_space(1))) void*)src,
                                   (__attribute__((address_space(3))) void*)lds, 16, 0, 0);
}

// wf layout (fragment-major): B-frag for (col-tile ct, k-step s) of the 320x256
// combined weight: element (col C = ct*16+cl, k = s*32+gf*8+j) lives at
// wf[((ct*8+s)*64 + gf*16+cl)*8 + j]. A wave's B-load = 64 lanes x 16B contiguous.
__device__ inline size_t wf_addr(int C, int kk) {
  int ct = C >> 4, cl = C & 15, s = kk >> 5, gf = (kk >> 3) & 3, j = kk & 7;
  return ((size_t)((ct * 8 + s) * 64 + gf * 16 + cl)) * 8 + j;
}

// ---------------- kernel 0a: weight casts ----------------
__global__ __launch_bounds__(256) void prep_kernel(const float* __restrict__ wq,
                                                   const float* __restrict__ wk,
                                                   const float* __restrict__ wo,
                                                   const float* __restrict__ wv,
                                                   unsigned short* __restrict__ wf,
                                                   unsigned short* __restrict__ wv_b,
                                                   unsigned short* __restrict__ woT_b) {
  int i = blockIdx.x * 256 + threadIdx.x;  // total 147456
  if (i < 16384) {
    int C = i >> 8, kk = i & 255;
    float v = (C < 32) ? wq[kk * 32 + C] * LOG2E : wk[kk * 32 + (C - 32)];
    wf[wf_addr(C, kk)] = f2bf(v);
  } else if (i < 81920) {
    int j = i - 16384;
    wv_b[j] = f2bf(wv[j]);
  } else {
    int j = i - 81920;  // woT_b[e2][e] = wo[e][e2]
    int e2 = j >> 8, e = j & 255;
    woT_b[j] = f2bf(wo[e * 256 + e2]);
  }
}

// ---------------- kernel 0b: Wvo^T = Wo^T . Wv^T -> wf tiles 4-19 (fragment-major) --
__global__ __launch_bounds__(256) void prep2_kernel(const unsigned short* __restrict__ woT_b,
                                                    const unsigned short* __restrict__ wv_b,
                                                    unsigned short* __restrict__ wf) {
  const int lane = threadIdx.x & 63, w = threadIdx.x >> 6;
  const int g = lane >> 4, li = lane & 15;
  const int m0 = blockIdx.x * 64 + w * 16;
  const unsigned short* arow = woT_b + (size_t)(m0 + li) * 256 + (g << 3);
  const unsigned short* brow = wv_b + (size_t)li * 256 + (g << 3);
  f32x4 acc[16] = {};
  for (int kk = 0; kk < 256; kk += 32) {
    short8 a = *reinterpret_cast<const short8*>(arow + kk);
#pragma unroll
    for (int ct = 0; ct < 16; ++ct) {
      short8 bb = *reinterpret_cast<const short8*>(brow + (size_t)ct * 16 * 256 + kk);
      acc[ct] = __builtin_amdgcn_mfma_f32_16x16x32_bf16(a, bb, acc[ct], 0, 0, 0);
    }
  }
#pragma unroll
  for (int ct = 0; ct < 16; ++ct)
#pragma unroll
    for (int r = 0; r < 4; ++r) {
      const int C = 64 + m0 + (g << 2) + r;
      const int kk = ct * 16 + li;
      wf[wf_addr(C, kk)] = f2bf(acc[ct][r]);
    }
}

// ---------------- kernel 1: fused QKVW projection (r13, validated) ----------------
__global__ __launch_bounds__(256, 2) void qkv_kernel(const float* __restrict__ x,
                                                     const unsigned short* __restrict__ wf,
                                                     unsigned short* __restrict__ q,
                                                     unsigned short* __restrict__ k,
                                                     unsigned short* __restrict__ vwT) {
  __shared__ __align__(16) unsigned short xs[64 * 256];  // 32KB, swizzled
  const int tid = threadIdx.x;
  const int l = tid & 63, w = tid >> 6;
  const int bx = blockIdx.x;
  const int g = l >> 4, li = l & 15;
  const int m0 = bx * 64;

  const unsigned short* wfb = wf + (size_t)(w * 5) * 4096;  // wave's 5 col-tiles

  short8 BA[5], BB[5];
#pragma unroll
  for (int c = 0; c < 5; ++c)
    BA[c] = *reinterpret_cast<const short8*>(wfb + ((size_t)(c * 8 + 0) * 64 + l) * 8);
#pragma unroll
  for (int c = 0; c < 5; ++c)
    BB[c] = *reinterpret_cast<const short8*>(wfb + ((size_t)(c * 8 + 1) * 64 + l) * 8);

  {
    const int row = tid >> 2, qtr = tid & 3;
    const float* src = x + (size_t)(m0 + row) * 256 + qtr * 64;
    unsigned short* dstrow = xs + row * 256;
#pragma unroll
    for (int jj = 0; jj < 8; ++jj) {
      f32x4 a0 = *reinterpret_cast<const f32x4*>(src + jj * 8);
      f32x4 a1 = *reinterpret_cast<const f32x4*>(src + jj * 8 + 4);
      union { unsigned u[4]; ushort8 v; } P;
      P.u[0] = cvt_pk_bf16(a0[0], a0[1]); P.u[1] = cvt_pk_bf16(a0[2], a0[3]);
      P.u[2] = cvt_pk_bf16(a1[0], a1[1]); P.u[3] = cvt_pk_bf16(a1[2], a1[3]);
      const int blk = (qtr * 8 + jj) ^ (row & 7);
      *reinterpret_cast<ushort8*>(dstrow + blk * 8) = P.v;
    }
  }
  __syncthreads();  // xs ready; read-only hereafter

  f32x4 acc[4][5] = {};

#define QSTEP(S, BV, WN, PREF)                                                       \
  {                                                                                  \
    asm volatile("s_waitcnt vmcnt(" WN ")" ::: "memory");                            \
    __builtin_amdgcn_sched_barrier(0);                                               \
    short8 a_[4];                                                                    \
    _Pragma("unroll") for (int mt = 0; mt < 4; ++mt) {                               \
      const int row = mt * 16 + li;                                                  \
      a_[mt] = *reinterpret_cast<const short8*>(                                     \
          xs + row * 256 + ((((S) * 4 + g) ^ (row & 7)) << 3));                      \
    }                                                                                \
    _Pragma("unroll") for (int mt = 0; mt < 4; ++mt)                                 \
        _Pragma("unroll") for (int c = 0; c < 5; ++c)                                \
            acc[mt][c] = __builtin_amdgcn_mfma_f32_16x16x32_bf16(a_[mt], BV[c],      \
                                                                 acc[mt][c], 0, 0, 0); \
    if (PREF) {                                                                      \
      _Pragma("unroll") for (int c = 0; c < 5; ++c)                                  \
          BV[c] = *reinterpret_cast<const short8*>(                                  \
              wfb + ((size_t)(c * 8 + (S) + 2) * 64 + l) * 8);                       \
    }                                                                                \
  }

  QSTEP(0, BA, "5", true)
  QSTEP(1, BB, "5", true)
  QSTEP(2, BA, "5", true)
  QSTEP(3, BB, "5", true)
  QSTEP(4, BA, "5", true)
  QSTEP(5, BB, "5", true)
  QSTEP(6, BA, "5", false)
  QSTEP(7, BB, "0", false)
#undef QSTEP

  const int bb_ = bx >> 6;
#pragma unroll
  for (int mt = 0; mt < 4; ++mt) {
    const int nloc = (bx & 63) * 64 + mt * 16 + (g << 2);
#pragma unroll
    for (int c = 0; c < 5; ++c) {
      const int Cg = w * 5 + c;
      if (Cg < 2) {
        const int col = Cg * 16 + li;
#pragma unroll
        for (int r = 0; r < 4; ++r)
          q[((size_t)bb_ * N_ + nloc + r) * D_ + col] = f2bf(acc[mt][c][r]);
      } else if (Cg < 4) {
        const int col = (Cg - 2) * 16 + li;
#pragma unroll
        for (int r = 0; r < 4; ++r)
          k[((size_t)bb_ * N_ + nloc + r) * D_ + col] = f2bf(acc[mt][c][r]);
      } else {
        const int vc = Cg * 16 + li - 64;
        union { unsigned u[2]; ushort4v v; } P;
        P.u[0] = cvt_pk_bf16(acc[mt][c][0], acc[mt][c][1]);
        P.u[1] = cvt_pk_bf16(acc[mt][c][2], acc[mt][c][3]);
        *reinterpret_cast<ushort4v*>(&vwT[((size_t)bb_ * C_ + vc) * N_ + nloc]) = P.v;
      }
    }
  }
}

// ---------------- kernel 2: flash attention, 64-kv chunks, kv-halves fused --------
// grid 256 x 512. blk: b = blk&7 (XCD pin), qt = blk>>3 (0..31). 8 waves:
// kvh = w>>2 (2048-kv half), gw = w&3 -> qg = gw>>1, ch = gw&1. Per kvh group:
// V[256c][64kv] double-buffered (2x32KB) + K[64kv][32d] (2x4KB); LDS 144KB ->
// 1 block/CU = 8 waves = 2/SIMD. Per iter (32 total, HALF of r14's 64):
// vmcnt(0) (only own chunk outstanding, landed a full iter ago) -> one s_barrier
// -> stage chunk i+1 (uniform 9 gll16/wave) -> compute 64 kv as two unrolled
// 32-kv sub-bodies (r14-validated math). V rows = 128B (full bank wrap), 8-block
// XOR swizzle pos = blk ^ (row&7) -> conflict-free per 8-lane phase. In-block
// kv-merge + normalize + x residual + fp32 store (r14-validated epilogue).
__global__ __launch_bounds__(512, 2) void flash_kernel(const unsigned short* __restrict__ q,
                                                       const unsigned short* __restrict__ k,
                                                       const unsigned short* __restrict__ vwT,
                                                       const float* __restrict__ x,
                                                       float* __restrict__ out) {
  __shared__ __align__(16) char smem[147456];  // V 2grp x 2buf x 32KB | K @131072 2x2x4KB
  const int tid = threadIdx.x;
  const int l = tid & 63, w_ = tid >> 6;       // 0..7
  const int kvh = w_ >> 2, gw = w_ & 3;
  const int qg = gw >> 1, ch = gw & 1;
  const int blk = blockIdx.x;
  const int b = blk & 7;
  const int qt = blk >> 3;                     // 0..31
  const int h = l >> 5, l31 = l & 31;
  const int R = kvh * 65536;

  const unsigned short* kb_ = k + (size_t)b * N_ * D_;
  const unsigned short* vb_ = vwT + (size_t)b * C_ * N_;

  // Q B-frags qb[qt2][ks]: col q = l31, k-dim = ks*16 + 8h + j
  const int qposb = qt * 128 + qg * 64;  // + qt2*32 + l31
  short8 qb[2][2];
#pragma unroll
  for (int qt2 = 0; qt2 < 2; ++qt2) {
    const size_t qoff = ((size_t)b * N_ + qposb + qt2 * 32 + l31) * D_ + h * 8;
    qb[qt2][0] = *reinterpret_cast<const short8*>(q + qoff);
    qb[qt2][1] = *reinterpret_cast<const short8*>(q + qoff + 16);
  }
  asm volatile("s_waitcnt vmcnt(0)" ::: "memory");  // clean vm counter before staging

  // V staging: wave gw stages channels gw*64..+63; granule t = 8 rows x 128B;
  // lane -> (row = l>>3, 16B-pos = l&7); source block = (l&7) ^ (row&7).
  const int vrow = l >> 3;
  const int vsrc = ((l & 7) ^ ((l >> 3) & 7)) << 3;  // elems
  // K staging: wave gw stages kv rows gw*16..+15; lane -> (row = l>>2, pos = l&3);
  // source block = (l&3) ^ ((row>>1)&3) = (l&3) ^ ((l>>3)&3).
  const int krow = l >> 2;
  const int ksrc = ((l & 3) ^ ((l >> 3) & 3)) << 3;  // elems
  const int kvbase = kvh * 2048;

#define STAGE(BUF, KV0)                                                           \
  {                                                                               \
    char* vd = smem + R + (BUF) * 32768 + gw * 8192;                              \
    _Pragma("unroll") for (int t = 0; t < 8; ++t)                                 \
        gll16(vb_ + (size_t)(gw * 64 + t * 8 + vrow) * N_ + (KV0) + vsrc,         \
              vd + t * 1024);                                                     \
    gll16(kb_ + (size_t)((KV0) + gw * 16 + krow) * D_ + ksrc,                     \
          smem + 131072 + kvh * 8192 + (BUF) * 4096 + gw * 1024);                 \
  }

  f32x16 o[4][2] = {};  // [ct][qt2]: O^T (32c x 32q), c = ch*128 + ct*32
  float lsum[2] = {0.f, 0.f};
  const f32x16 z16 = {};
  const int kkey = (l31 >> 1) & 3;

  STAGE(0, kvbase)

  for (int i = 0; i < 32; ++i) {
    const int buf = i & 1;
    asm volatile("s_waitcnt vmcnt(0)" ::: "memory");  // chunk i landed (1 iter ago)
    __builtin_amdgcn_sched_barrier(0);
    __builtin_amdgcn_s_barrier();  // all waves' chunk-i loads landed; buf^1 reads done
    if (i < 31) STAGE(buf ^ 1, kvbase + (i + 1) * 64)
    const char* Vb = smem + R + buf * 32768;
    const char* Kb = smem + 131072 + kvh * 8192 + buf * 4096;
#pragma unroll
    for (int kvt = 0; kvt < 2; ++kvt) {
      // ---- S^T = K.Q^T for kv sub-chunk kvt*32..+31, both qt2 back-to-back ----
      const int krow32 = (kvt * 32 + l31) * 64;
      short8 ka0 = *reinterpret_cast<const short8*>(Kb + krow32 + (((0 + h) ^ kkey) << 4));
      short8 ka1 = *reinterpret_cast<const short8*>(Kb + krow32 + (((2 + h) ^ kkey) << 4));
      f32x16 s0 = __builtin_amdgcn_mfma_f32_32x32x16_bf16(ka0, qb[0][0], z16, 0, 0, 0);
      s0 = __builtin_amdgcn_mfma_f32_32x32x16_bf16(ka1, qb[0][1], s0, 0, 0, 0);
      f32x16 s1 = __builtin_amdgcn_mfma_f32_32x32x16_bf16(ka0, qb[1][0], z16, 0, 0, 0);
      s1 = __builtin_amdgcn_mfma_f32_32x32x16_bf16(ka1, qb[1][1], s1, 0, 0, 0);
      short8 pf[2][2];
#pragma unroll
      for (int r = 0; r < 16; ++r) s0[r] = exp2_fast(s0[r]);
      if (ch == 0)
        lsum[0] += (((s0[0] + s0[1]) + (s0[2] + s0[3])) + ((s0[4] + s0[5]) + (s0[6] + s0[7]))) +
                   (((s0[8] + s0[9]) + (s0[10] + s0[11])) + ((s0[12] + s0[13]) + (s0[14] + s0[15])));
      {
        unsigned x0 = cvt_pk_bf16(s0[0], s0[1]),   y0 = cvt_pk_bf16(s0[4], s0[5]);
        unsigned x1 = cvt_pk_bf16(s0[2], s0[3]),   y1 = cvt_pk_bf16(s0[6], s0[7]);
        unsigned x2 = cvt_pk_bf16(s0[8], s0[9]),   y2 = cvt_pk_bf16(s0[12], s0[13]);
        unsigned x3 = cvt_pk_bf16(s0[10], s0[11]), y3 = cvt_pk_bf16(s0[14], s0[15]);
        permlane32_swap(x0, y0); permlane32_swap(x1, y1);
        permlane32_swap(x2, y2); permlane32_swap(x3, y3);
        union U { unsigned u[4]; short8 v; };
        U u0; u0.u[0] = x0; u0.u[1] = x1; u0.u[2] = y0; u0.u[3] = y1;  // kv 0-15
        U u1; u1.u[0] = x2; u1.u[1] = x3; u1.u[2] = y2; u1.u[3] = y3;  // kv 16-31
        pf[0][0] = u0.v; pf[0][1] = u1.v;
      }
#pragma unroll
      for (int r = 0; r < 16; ++r) s1[r] = exp2_fast(s1[r]);
      if (ch == 0)
        lsum[1] += (((s1[0] + s1[1]) + (s1[2] + s1[3])) + ((s1[4] + s1[5]) + (s1[6] + s1[7]))) +
                   (((s1[8] + s1[9]) + (s1[10] + s1[11])) + ((s1[12] + s1[13]) + (s1[14] + s1[15])));
      {
        unsigned x0 = cvt_pk_bf16(s1[0], s1[1]),   y0 = cvt_pk_bf16(s1[4], s1[5]);
        unsigned x1 = cvt_pk_bf16(s1[2], s1[3]),   y1 = cvt_pk_bf16(s1[6], s1[7]);
        unsigned x2 = cvt_pk_bf16(s1[8], s1[9]),   y2 = cvt_pk_bf16(s1[12], s1[13]);
        unsigned x3 = cvt_pk_bf16(s1[10], s1[11]), y3 = cvt_pk_bf16(s1[14], s1[15]);
        permlane32_swap(x0, y0); permlane32_swap(x1, y1);
        permlane32_swap(x2, y2); permlane32_swap(x3, y3);
        union U { unsigned u[4]; short8 v; };
        U u0; u0.u[0] = x0; u0.u[1] = x1; u0.u[2] = y0; u0.u[3] = y1;
        U u1; u1.u[0] = x2; u1.u[1] = x3; u1.u[2] = y2; u1.u[3] = y3;
        pf[1][0] = u0.v; pf[1][1] = u1.v;
      }
      // ---- PV: O^T += V^T . P^T (va feeds both qt2); blocks kvt*4+{0,2}+h ----
      __builtin_amdgcn_s_setprio(1);
#pragma unroll
      for (int ct = 0; ct < 4; ++ct) {
        const int rl = ch * 128 + ct * 32 + l31;
        const int vkey = rl & 7;
        const int rb = rl * 128;
        short8 va0 = *reinterpret_cast<const short8*>(Vb + rb + (((kvt * 4 + 0 + h) ^ vkey) << 4));
        short8 va1 = *reinterpret_cast<const short8*>(Vb + rb + (((kvt * 4 + 2 + h) ^ vkey) << 4));
        o[ct][0] = __builtin_amdgcn_mfma_f32_32x32x16_bf16(va0, pf[0][0], o[ct][0], 0, 0, 0);
        o[ct][0] = __builtin_amdgcn_mfma_f32_32x32x16_bf16(va1, pf[0][1], o[ct][0], 0, 0, 0);
        o[ct][1] = __builtin_amdgcn_mfma_f32_32x32x16_bf16(va0, pf[1][0], o[ct][1], 0, 0, 0);
        o[ct][1] = __builtin_amdgcn_mfma_f32_32x32x16_bf16(va1, pf[1][1], o[ct][1], 0, 0, 0);
      }
      __builtin_amdgcn_s_setprio(0);
    }
  }

  // ---- in-block kv-merge + normalize + residual + final store ----
  lsum[0] += __shfl_xor(lsum[0], 32);
  lsum[1] += __shfl_xor(lsum[1], 32);
  __syncthreads();  // final chunk reads complete; LDS reusable
  float* lb = reinterpret_cast<float*>(smem + 131072);  // lsums[2][2][64] in K region
  if (ch == 0 && h == 0) {
    lb[kvh * 128 + qg * 64 + l31] = lsum[0];
    lb[kvh * 128 + qg * 64 + 32 + l31] = lsum[1];
  }
  if (kvh == 1) {
    char* ob = smem + gw * 16384;  // wave slot: 64 bf16-pairs/lane, b128 lane-major
    int pg = 0;
#pragma unroll
    for (int ct = 0; ct < 4; ++ct)
#pragma unroll
      for (int qt2 = 0; qt2 < 2; ++qt2)
#pragma unroll
        for (int jg = 0; jg < 2; ++jg) {
          u32x4 t;
#pragma unroll
          for (int e = 0; e < 4; ++e) {
            const int j = jg * 4 + e;
            t[e] = cvt_pk_bf16(o[ct][qt2][2 * j], o[ct][qt2][2 * j + 1]);
          }
          *reinterpret_cast<u32x4*>(ob + pg * 1024 + l * 16) = t;
          ++pg;
        }
  }
  __syncthreads();
  if (kvh == 0) {
    float inv[2];
#pragma unroll
    for (int qt2 = 0; qt2 < 2; ++qt2)
      inv[qt2] = 1.0f / (lb[qg * 64 + qt2 * 32 + l31] + lb[128 + qg * 64 + qt2 * 32 + l31]);
    const char* ob = smem + gw * 16384;
    int pg = 0;
#pragma unroll
    for (int ct = 0; ct < 4; ++ct)
#pragma unroll
      for (int qt2 = 0; qt2 < 2; ++qt2)
#pragma unroll
        for (int jg = 0; jg < 2; ++jg) {
          u32x4 t = *reinterpret_cast<const u32x4*>(ob + pg * 1024 + l * 16);
          ++pg;
#pragma unroll
          for (int e = 0; e < 4; ++e) {
            const int j = jg * 4 + e;
            o[ct][qt2][2 * j]     += bf2f((unsigned short)(t[e] & 0xffffu));
            o[ct][qt2][2 * j + 1] += bf2f((unsigned short)(t[e] >> 16));
          }
        }
#pragma unroll
    for (int qt2 = 0; qt2 < 2; ++qt2) {
      const size_t rowbase = ((size_t)b * N_ + qposb + qt2 * 32 + l31) * C_ + ch * 128;
#pragma unroll
      for (int ct = 0; ct < 4; ++ct)
#pragma unroll
        for (int j = 0; j < 8; ++j) {
          const int c = ct * 32 + 2 * (j & 1) + 8 * (j >> 1) + 4 * h;
          f32x2 xr = *reinterpret_cast<const f32x2*>(x + rowbase + c);
          f32x2 t;
          t[0] = o[ct][qt2][2 * j] * inv[qt2] + xr[0];
          t[1] = o[ct][qt2][2 * j + 1] * inv[qt2] + xr[1];
          *reinterpret_cast<f32x2*>(out + rowbase + c) = t;
        }
    }
  }
#undef STAGE
}

extern "C" void kernel_launch(void* const* d_in, const int* in_sizes, int n_in,
                              void* d_out, int out_size, void* d_ws, size_t ws_size,
                              hipStream_t stream) {
  const float* x  = (const float*)d_in[0];
  const float* wq = (const float*)d_in[1];
  const float* wk = (const float*)d_in[2];
  const float* wv = (const float*)d_in[3];
  const float* wo = (const float*)d_in[4];
  float* out = (float*)d_out;
  char* ws = (char*)d_ws;
  unsigned short* wf    = (unsigned short*)(ws + 0);         // 163840 B (frag-major W)
  unsigned short* wv_b  = (unsigned short*)(ws + 163840);    // 131072 B
  unsigned short* woT_b = (unsigned short*)(ws + 294912);    // 131072 B
  unsigned short* q     = (unsigned short*)(ws + 425984);    // 2 MB
  unsigned short* k     = (unsigned short*)(ws + 2523136);   // 2 MB
  unsigned short* vwT   = (unsigned short*)(ws + 4620288);   // 16 MB (total ~20.4 MB)

  prep_kernel<<<576, 256, 0, stream>>>(wq, wk, wo, wv, wf, wv_b, woT_b);
  prep2_kernel<<<4, 256, 0, stream>>>(woT_b, wv_b, wf);
  qkv_kernel<<<512, 256, 0, stream>>>(x, wf, q, k, vwT);
  flash_kernel<<<256, 512, 0, stream>>>(q, k, vwT, x, out);
}

// Round 16
// 125.421 us; speedup vs baseline: 1.4458x; 1.0821x over previous
//
#include <hip/hip_runtime.h>
#include <hip/hip_bf16.h>
#include <stdint.h>

typedef __attribute__((ext_vector_type(8))) short short8;
typedef __attribute__((ext_vector_type(8))) unsigned short ushort8;
typedef __attribute__((ext_vector_type(4))) unsigned short ushort4v;
typedef __attribute__((ext_vector_type(4))) unsigned u32x4;
typedef __attribute__((ext_vector_type(2))) float f32x2;
typedef __attribute__((ext_vector_type(4))) float f32x4;
typedef __attribute__((ext_vector_type(16))) float f32x16;

#define B_ 8
#define N_ 4096
#define C_ 256
#define D_ 32
#define LOG2E 1.44269504088896f

__device__ inline unsigned short f2bf(float f) {
  union { float f; unsigned u; } v; v.f = f;
  unsigned r = v.u + 0x7fffu + ((v.u >> 16) & 1u);
  return (unsigned short)(r >> 16);
}
__device__ inline float bf2f(unsigned short u) {
  return __uint_as_float(((unsigned)u) << 16);
}
__device__ inline float exp2_fast(float x) {
  float r; asm("v_exp_f32 %0, %1" : "=v"(r) : "v"(x)); return r;
}
__device__ inline unsigned cvt_pk_bf16(float lo, float hi) {
  unsigned r; asm("v_cvt_pk_bf16_f32 %0, %1, %2" : "=v"(r) : "v"(lo), "v"(hi)); return r;
}
// a <- [a.l0-31 | b.l0-31], b <- [a.l32-63 | b.l32-63]
__device__ inline void permlane32_swap(unsigned& a, unsigned& b) {
  asm volatile("v_permlane32_swap_b32 %0, %1" : "+v"(a), "+v"(b));
}
__device__ inline void gll16(const unsigned short* src, void* lds) {
  __builtin_amdgcn_global_load_lds((const __attribute__((address_space(1))) void*)src,
                                   (__attribute__((address_space(3))) void*)lds, 16, 0, 0);
}

// wf layout (fragment-major): B-frag for (col-tile ct, k-step s) of the 320x256
// combined weight: element (col C = ct*16+cl, k = s*32+gf*8+j) lives at
// wf[((ct*8+s)*64 + gf*16+cl)*8 + j]. A wave's B-load = 64 lanes x 16B contiguous.
__device__ inline size_t wf_addr(int C, int kk) {
  int ct = C >> 4, cl = C & 15, s = kk >> 5, gf = (kk >> 3) & 3, j = kk & 7;
  return ((size_t)((ct * 8 + s) * 64 + gf * 16 + cl)) * 8 + j;
}

// ---------------- kernel 0a: weight casts ----------------
__global__ __launch_bounds__(256) void prep_kernel(const float* __restrict__ wq,
                                                   const float* __restrict__ wk,
                                                   const float* __restrict__ wo,
                                                   const float* __restrict__ wv,
                                                   unsigned short* __restrict__ wf,
                                                   unsigned short* __restrict__ wv_b,
                                                   unsigned short* __restrict__ woT_b) {
  int i = blockIdx.x * 256 + threadIdx.x;  // total 147456
  if (i < 16384) {
    int C = i >> 8, kk = i & 255;
    float v = (C < 32) ? wq[kk * 32 + C] * LOG2E : wk[kk * 32 + (C - 32)];
    wf[wf_addr(C, kk)] = f2bf(v);
  } else if (i < 81920) {
    int j = i - 16384;
    wv_b[j] = f2bf(wv[j]);
  } else {
    int j = i - 81920;  // woT_b[e2][e] = wo[e][e2]
    int e2 = j >> 8, e = j & 255;
    woT_b[j] = f2bf(wo[e * 256 + e2]);
  }
}

// ---------------- kernel 0b: Wvo^T = Wo^T . Wv^T -> wf tiles 4-19 (fragment-major) --
__global__ __launch_bounds__(256) void prep2_kernel(const unsigned short* __restrict__ woT_b,
                                                    const unsigned short* __restrict__ wv_b,
                                                    unsigned short* __restrict__ wf) {
  const int lane = threadIdx.x & 63, w = threadIdx.x >> 6;
  const int g = lane >> 4, li = lane & 15;
  const int m0 = blockIdx.x * 64 + w * 16;
  const unsigned short* arow = woT_b + (size_t)(m0 + li) * 256 + (g << 3);
  const unsigned short* brow = wv_b + (size_t)li * 256 + (g << 3);
  f32x4 acc[16] = {};
  for (int kk = 0; kk < 256; kk += 32) {
    short8 a = *reinterpret_cast<const short8*>(arow + kk);
#pragma unroll
    for (int ct = 0; ct < 16; ++ct) {
      short8 bb = *reinterpret_cast<const short8*>(brow + (size_t)ct * 16 * 256 + kk);
      acc[ct] = __builtin_amdgcn_mfma_f32_16x16x32_bf16(a, bb, acc[ct], 0, 0, 0);
    }
  }
#pragma unroll
  for (int ct = 0; ct < 16; ++ct)
#pragma unroll
    for (int r = 0; r < 4; ++r) {
      const int C = 64 + m0 + (g << 2) + r;
      const int kk = ct * 16 + li;
      wf[wf_addr(C, kk)] = f2bf(acc[ct][r]);
    }
}

// ---------------- kernel 1: fused QKVW projection (r13, validated) ----------------
__global__ __launch_bounds__(256, 2) void qkv_kernel(const float* __restrict__ x,
                                                     const unsigned short* __restrict__ wf,
                                                     unsigned short* __restrict__ q,
                                                     unsigned short* __restrict__ k,
                                                     unsigned short* __restrict__ vwT) {
  __shared__ __align__(16) unsigned short xs[64 * 256];  // 32KB, swizzled
  const int tid = threadIdx.x;
  const int l = tid & 63, w = tid >> 6;
  const int bx = blockIdx.x;
  const int g = l >> 4, li = l & 15;
  const int m0 = bx * 64;

  const unsigned short* wfb = wf + (size_t)(w * 5) * 4096;  // wave's 5 col-tiles

  short8 BA[5], BB[5];
#pragma unroll
  for (int c = 0; c < 5; ++c)
    BA[c] = *reinterpret_cast<const short8*>(wfb + ((size_t)(c * 8 + 0) * 64 + l) * 8);
#pragma unroll
  for (int c = 0; c < 5; ++c)
    BB[c] = *reinterpret_cast<const short8*>(wfb + ((size_t)(c * 8 + 1) * 64 + l) * 8);

  {
    const int row = tid >> 2, qtr = tid & 3;
    const float* src = x + (size_t)(m0 + row) * 256 + qtr * 64;
    unsigned short* dstrow = xs + row * 256;
#pragma unroll
    for (int jj = 0; jj < 8; ++jj) {
      f32x4 a0 = *reinterpret_cast<const f32x4*>(src + jj * 8);
      f32x4 a1 = *reinterpret_cast<const f32x4*>(src + jj * 8 + 4);
      union { unsigned u[4]; ushort8 v; } P;
      P.u[0] = cvt_pk_bf16(a0[0], a0[1]); P.u[1] = cvt_pk_bf16(a0[2], a0[3]);
      P.u[2] = cvt_pk_bf16(a1[0], a1[1]); P.u[3] = cvt_pk_bf16(a1[2], a1[3]);
      const int blk = (qtr * 8 + jj) ^ (row & 7);
      *reinterpret_cast<ushort8*>(dstrow + blk * 8) = P.v;
    }
  }
  __syncthreads();  // xs ready; read-only hereafter

  f32x4 acc[4][5] = {};

#define QSTEP(S, BV, WN, PREF)                                                       \
  {                                                                                  \
    asm volatile("s_waitcnt vmcnt(" WN ")" ::: "memory");                            \
    __builtin_amdgcn_sched_barrier(0);                                               \
    short8 a_[4];                                                                    \
    _Pragma("unroll") for (int mt = 0; mt < 4; ++mt) {                               \
      const int row = mt * 16 + li;                                                  \
      a_[mt] = *reinterpret_cast<const short8*>(                                     \
          xs + row * 256 + ((((S) * 4 + g) ^ (row & 7)) << 3));                      \
    }                                                                                \
    _Pragma("unroll") for (int mt = 0; mt < 4; ++mt)                                 \
        _Pragma("unroll") for (int c = 0; c < 5; ++c)                                \
            acc[mt][c] = __builtin_amdgcn_mfma_f32_16x16x32_bf16(a_[mt], BV[c],      \
                                                                 acc[mt][c], 0, 0, 0); \
    if (PREF) {                                                                      \
      _Pragma("unroll") for (int c = 0; c < 5; ++c)                                  \
          BV[c] = *reinterpret_cast<const short8*>(                                  \
              wfb + ((size_t)(c * 8 + (S) + 2) * 64 + l) * 8);                       \
    }                                                                                \
  }

  QSTEP(0, BA, "5", true)
  QSTEP(1, BB, "5", true)
  QSTEP(2, BA, "5", true)
  QSTEP(3, BB, "5", true)
  QSTEP(4, BA, "5", true)
  QSTEP(5, BB, "5", true)
  QSTEP(6, BA, "5", false)
  QSTEP(7, BB, "0", false)
#undef QSTEP

  const int bb_ = bx >> 6;
#pragma unroll
  for (int mt = 0; mt < 4; ++mt) {
    const int nloc = (bx & 63) * 64 + mt * 16 + (g << 2);
#pragma unroll
    for (int c = 0; c < 5; ++c) {
      const int Cg = w * 5 + c;
      if (Cg < 2) {
        const int col = Cg * 16 + li;
#pragma unroll
        for (int r = 0; r < 4; ++r)
          q[((size_t)bb_ * N_ + nloc + r) * D_ + col] = f2bf(acc[mt][c][r]);
      } else if (Cg < 4) {
        const int col = (Cg - 2) * 16 + li;
#pragma unroll
        for (int r = 0; r < 4; ++r)
          k[((size_t)bb_ * N_ + nloc + r) * D_ + col] = f2bf(acc[mt][c][r]);
      } else {
        const int vc = Cg * 16 + li - 64;
        union { unsigned u[2]; ushort4v v; } P;
        P.u[0] = cvt_pk_bf16(acc[mt][c][0], acc[mt][c][1]);
        P.u[1] = cvt_pk_bf16(acc[mt][c][2], acc[mt][c][3]);
        *reinterpret_cast<ushort4v*>(&vwT[((size_t)bb_ * C_ + vc) * N_ + nloc]) = P.v;
      }
    }
  }
}

// ---------------- kernel 2: flash attention, de-duplicated S (32q x 256c waves) ----
// grid 256 x 512. blk: b = blk&7 (XCD pin), qt = blk>>3 (0..31). 8 waves:
// kvh = w>>2 (2048-kv half), qg = w&3 (DISTINCT 32q strip). Each wave computes S
// for its own strip exactly once (no ch duplication: exp count halves vs r15) and
// the FULL 256c PV (acc = 8 x f32x16 = 128 AGPR, unchanged). V[256c][64kv] dbuf
// (2x32KB) + K[64kv][32d] (2x4KB) per kvh group; per iter (32): vmcnt(0) ->
// s_barrier -> stage chunk i+1 (uniform 9 gll16/wave) -> two 32-kv sub-bodies.
// Swizzles r15-validated. In-block kv-merge + normalize + residual + fp32 store.
__global__ __launch_bounds__(512, 2) void flash_kernel(const unsigned short* __restrict__ q,
                                                       const unsigned short* __restrict__ k,
                                                       const unsigned short* __restrict__ vwT,
                                                       const float* __restrict__ x,
                                                       float* __restrict__ out) {
  __shared__ __align__(16) char smem[147456];  // V 2grp x 2buf x 32KB | K @131072 2x2x4KB
  const int tid = threadIdx.x;
  const int l = tid & 63, w_ = tid >> 6;       // 0..7
  const int kvh = w_ >> 2, qg = w_ & 3;
  const int blk = blockIdx.x;
  const int b = blk & 7;
  const int qt = blk >> 3;                     // 0..31
  const int h = l >> 5, l31 = l & 31;
  const int R = kvh * 65536;

  const unsigned short* kb_ = k + (size_t)b * N_ * D_;
  const unsigned short* vb_ = vwT + (size_t)b * C_ * N_;

  // Q B-frags: col q = l31, k-dim = ks*16 + 8h + j  (one 32q strip per wave)
  const int qposb = qt * 128 + qg * 32;  // + l31
  const size_t qoff = ((size_t)b * N_ + qposb + l31) * D_ + h * 8;
  const short8 qb0 = *reinterpret_cast<const short8*>(q + qoff);
  const short8 qb1 = *reinterpret_cast<const short8*>(q + qoff + 16);
  asm volatile("s_waitcnt vmcnt(0)" ::: "memory");  // clean vm counter before staging

  // V staging: wave qg stages channels qg*64..+63; granule t = 8 rows x 128B;
  // lane -> (row = l>>3, 16B-pos = l&7); source block = (l&7) ^ (row&7).
  const int vrow = l >> 3;
  const int vsrc = ((l & 7) ^ ((l >> 3) & 7)) << 3;  // elems
  // K staging: wave qg stages kv rows qg*16..+15; lane -> (row = l>>2, pos = l&3).
  const int krow = l >> 2;
  const int ksrc = ((l & 3) ^ ((l >> 3) & 3)) << 3;  // elems
  const int kvbase = kvh * 2048;

#define STAGE(BUF, KV0)                                                           \
  {                                                                               \
    char* vd = smem + R + (BUF) * 32768 + qg * 8192;                              \
    _Pragma("unroll") for (int t = 0; t < 8; ++t)                                 \
        gll16(vb_ + (size_t)(qg * 64 + t * 8 + vrow) * N_ + (KV0) + vsrc,         \
              vd + t * 1024);                                                     \
    gll16(kb_ + (size_t)((KV0) + qg * 16 + krow) * D_ + ksrc,                     \
          smem + 131072 + kvh * 8192 + (BUF) * 4096 + qg * 1024);                 \
  }

  f32x16 o[8] = {};  // [ct]: O^T (32c x 32q), c = ct*32 + ...
  float lsum = 0.f;
  const f32x16 z16 = {};
  const int kkey = (l31 >> 1) & 3;

  STAGE(0, kvbase)

  for (int i = 0; i < 32; ++i) {
    const int buf = i & 1;
    asm volatile("s_waitcnt vmcnt(0)" ::: "memory");  // chunk i landed (1 iter ago)
    __builtin_amdgcn_sched_barrier(0);
    __builtin_amdgcn_s_barrier();  // all waves' chunk-i loads landed; buf^1 reads done
    if (i < 31) STAGE(buf ^ 1, kvbase + (i + 1) * 64)
    const char* Vb = smem + R + buf * 32768;
    const char* Kb = smem + 131072 + kvh * 8192 + buf * 4096;
#pragma unroll
    for (int kvt = 0; kvt < 2; ++kvt) {
      // ---- S^T = K.Q^T for kv sub-chunk kvt*32..+31 (this wave's 32q only) ----
      const int krow32 = (kvt * 32 + l31) * 64;
      short8 ka0 = *reinterpret_cast<const short8*>(Kb + krow32 + (((0 + h) ^ kkey) << 4));
      short8 ka1 = *reinterpret_cast<const short8*>(Kb + krow32 + (((2 + h) ^ kkey) << 4));
      f32x16 s = __builtin_amdgcn_mfma_f32_32x32x16_bf16(ka0, qb0, z16, 0, 0, 0);
      s = __builtin_amdgcn_mfma_f32_32x32x16_bf16(ka1, qb1, s, 0, 0, 0);
#pragma unroll
      for (int r = 0; r < 16; ++r) s[r] = exp2_fast(s[r]);
      lsum += (((s[0] + s[1]) + (s[2] + s[3])) + ((s[4] + s[5]) + (s[6] + s[7]))) +
              (((s[8] + s[9]) + (s[10] + s[11])) + ((s[12] + s[13]) + (s[14] + s[15])));
      short8 pf0, pf1;
      {
        unsigned x0 = cvt_pk_bf16(s[0], s[1]),   y0 = cvt_pk_bf16(s[4], s[5]);
        unsigned x1 = cvt_pk_bf16(s[2], s[3]),   y1 = cvt_pk_bf16(s[6], s[7]);
        unsigned x2 = cvt_pk_bf16(s[8], s[9]),   y2 = cvt_pk_bf16(s[12], s[13]);
        unsigned x3 = cvt_pk_bf16(s[10], s[11]), y3 = cvt_pk_bf16(s[14], s[15]);
        permlane32_swap(x0, y0); permlane32_swap(x1, y1);
        permlane32_swap(x2, y2); permlane32_swap(x3, y3);
        union U { unsigned u[4]; short8 v; };
        U u0; u0.u[0] = x0; u0.u[1] = x1; u0.u[2] = y0; u0.u[3] = y1;  // kv 0-15
        U u1; u1.u[0] = x2; u1.u[1] = x3; u1.u[2] = y2; u1.u[3] = y3;  // kv 16-31
        pf0 = u0.v; pf1 = u1.v;
      }
      // ---- PV over FULL 256c: O^T += V^T . P^T ----
      __builtin_amdgcn_s_setprio(1);
#pragma unroll
      for (int ct = 0; ct < 8; ++ct) {
        const int rl = ct * 32 + l31;
        const int vkey = rl & 7;
        const int rb = rl * 128;
        short8 va0 = *reinterpret_cast<const short8*>(Vb + rb + (((kvt * 4 + 0 + h) ^ vkey) << 4));
        short8 va1 = *reinterpret_cast<const short8*>(Vb + rb + (((kvt * 4 + 2 + h) ^ vkey) << 4));
        o[ct] = __builtin_amdgcn_mfma_f32_32x32x16_bf16(va0, pf0, o[ct], 0, 0, 0);
        o[ct] = __builtin_amdgcn_mfma_f32_32x32x16_bf16(va1, pf1, o[ct], 0, 0, 0);
      }
      __builtin_amdgcn_s_setprio(0);
    }
  }

  // ---- in-block kv-merge + normalize + residual + final store ----
  lsum += __shfl_xor(lsum, 32);
  __syncthreads();  // final chunk reads complete; LDS reusable
  float* lb = reinterpret_cast<float*>(smem + 131072);  // lsums[2][4][32] in K region
  if (h == 0) lb[kvh * 128 + qg * 32 + l31] = lsum;
  if (kvh == 1) {
    char* ob = smem + qg * 16384;  // wave slot: 64 bf16-pairs/lane, b128 lane-major
    int pg = 0;
#pragma unroll
    for (int ct = 0; ct < 8; ++ct)
#pragma unroll
      for (int jg = 0; jg < 2; ++jg) {
        u32x4 t;
#pragma unroll
        for (int e = 0; e < 4; ++e) {
          const int j = jg * 4 + e;
          t[e] = cvt_pk_bf16(o[ct][2 * j], o[ct][2 * j + 1]);
        }
        *reinterpret_cast<u32x4*>(ob + pg * 1024 + l * 16) = t;
        ++pg;
      }
  }
  __syncthreads();
  if (kvh == 0) {
    const float inv = 1.0f / (lb[qg * 32 + l31] + lb[128 + qg * 32 + l31]);
    const char* ob = smem + qg * 16384;
    int pg = 0;
#pragma unroll
    for (int ct = 0; ct < 8; ++ct)
#pragma unroll
      for (int jg = 0; jg < 2; ++jg) {
        u32x4 t = *reinterpret_cast<const u32x4*>(ob + pg * 1024 + l * 16);
        ++pg;
#pragma unroll
        for (int e = 0; e < 4; ++e) {
          const int j = jg * 4 + e;
          o[ct][2 * j]     += bf2f((unsigned short)(t[e] & 0xffffu));
          o[ct][2 * j + 1] += bf2f((unsigned short)(t[e] >> 16));
        }
      }
    const size_t rowbase = ((size_t)b * N_ + qposb + l31) * C_;
#pragma unroll
    for (int ct = 0; ct < 8; ++ct)
#pragma unroll
      for (int j = 0; j < 8; ++j) {
        const int c = ct * 32 + 2 * (j & 1) + 8 * (j >> 1) + 4 * h;
        f32x2 xr = *reinterpret_cast<const f32x2*>(x + rowbase + c);
        f32x2 t;
        t[0] = o[ct][2 * j] * inv + xr[0];
        t[1] = o[ct][2 * j + 1] * inv + xr[1];
        *reinterpret_cast<f32x2*>(out + rowbase + c) = t;
      }
  }
#undef STAGE
}

extern "C" void kernel_launch(void* const* d_in, const int* in_sizes, int n_in,
                              void* d_out, int out_size, void* d_ws, size_t ws_size,
                              hipStream_t stream) {
  const float* x  = (const float*)d_in[0];
  const float* wq = (const float*)d_in[1];
  const float* wk = (const float*)d_in[2];
  const float* wv = (const float*)d_in[3];
  const float* wo = (const float*)d_in[4];
  float* out = (float*)d_out;
  char* ws = (char*)d_ws;
  unsigned short* wf    = (unsigned short*)(ws + 0);         // 163840 B (frag-major W)
  unsigned short* wv_b  = (unsigned short*)(ws + 163840);    // 131072 B
  unsigned short* woT_b = (unsigned short*)(ws + 294912);    // 131072 B
  unsigned short* q     = (unsigned short*)(ws + 425984);    // 2 MB
  unsigned short* k     = (unsigned short*)(ws + 2523136);   // 2 MB
  unsigned short* vwT   = (unsigned short*)(ws + 4620288);   // 16 MB (total ~20.4 MB)

  prep_kernel<<<576, 256, 0, stream>>>(wq, wk, wo, wv, wf, wv_b, woT_b);
  prep2_kernel<<<4, 256, 0, stream>>>(woT_b, wv_b, wf);
  qkv_kernel<<<512, 256, 0, stream>>>(x, wf, q, k, vwT);
  flash_kernel<<<256, 512, 0, stream>>>(q, k, vwT, x, out);
}